// Round 1
// baseline (7681.994 us; speedup 1.0000x reference)
//
#include <hip/hip_runtime.h>
#include <hip/hip_bf16.h>
#include <hip/hip_cooperative_groups.h>

namespace cg = cooperative_groups;

// Problem dims
#define Bb_ 32
#define Tt_ 100
#define Ss_ 512
#define Ee_ 1024
#define Hh_ 512
#define Vv_ 8192
#define NHh_ 4
#define HDd_ 128

// ---------------------------------------------------------------------------
// Generic tiled fp32 GEMM: C = A @ op(B) + bias1 + bias2, optional relu/scale.
// A: [M][K] row-major (lda). B: transB=1 -> [N][K] (ldb); transB=0 -> [K][N].
// Batched via blockIdx.z: z -> (bz = z/NH, hz = z%NH), offsets = bz*s?b + hz*s?h.
// out_mode 0: C[bz,hz
//  base][m*ldc + n];  out_mode 1: xg scatter -> C[((m%100)*N + n)*32 + m/100]
// ---------------------------------------------------------------------------
__global__ __launch_bounds__(256) void gemm_kernel(
    const float* __restrict__ A, int lda, long sAb, long sAh,
    const float* __restrict__ B, int ldb, long sBb, long sBh, int transB,
    float* __restrict__ C, int ldc, long sCb, long sCh,
    int M, int N, int K, int NH,
    const float* __restrict__ bias1, const float* __restrict__ bias2,
    int relu, float post_scale, int out_mode)
{
    __shared__ float As[16][64];
    __shared__ float Bs[16][64];
    const int z = blockIdx.z;
    const int bz = z / NH, hz = z % NH;
    const float* Ab = A + (long)bz * sAb + (long)hz * sAh;
    const float* Bbp = B + (long)bz * sBb + (long)hz * sBh;
    float* Cb = C + (long)bz * sCb + (long)hz * sCh;

    const int row0 = blockIdx.y * 64, col0 = blockIdx.x * 64;
    const int t = threadIdx.x;
    const int ar = t >> 2, ac = (t & 3) << 2;
    const int ty = t >> 4, tx = t & 15;

    float acc[4][4] = {};

    for (int k0 = 0; k0 < K; k0 += 16) {
        int am = row0 + ar; if (am >= M) am = M - 1;
        const float4 av = *(const float4*)(Ab + (long)am * lda + k0 + ac);
        float4 bv;
        if (transB) {
            bv = *(const float4*)(Bbp + (long)(col0 + ar) * ldb + k0 + ac);
        } else {
            bv = *(const float4*)(Bbp + (long)(k0 + ty) * ldb + col0 + (tx << 2));
        }
        __syncthreads();
        As[ac + 0][ar] = av.x; As[ac + 1][ar] = av.y;
        As[ac + 2][ar] = av.z; As[ac + 3][ar] = av.w;
        if (transB) {
            Bs[ac + 0][ar] = bv.x; Bs[ac + 1][ar] = bv.y;
            Bs[ac + 2][ar] = bv.z; Bs[ac + 3][ar] = bv.w;
        } else {
            *(float4*)&Bs[ty][tx << 2] = bv;
        }
        __syncthreads();
#pragma unroll
        for (int kk = 0; kk < 16; ++kk) {
            const float4 a4 = *(const float4*)&As[kk][ty << 2];
            const float4 b4 = *(const float4*)&Bs[kk][tx << 2];
            acc[0][0] = fmaf(a4.x, b4.x, acc[0][0]);
            acc[0][1] = fmaf(a4.x, b4.y, acc[0][1]);
            acc[0][2] = fmaf(a4.x, b4.z, acc[0][2]);
            acc[0][3] = fmaf(a4.x, b4.w, acc[0][3]);
            acc[1][0] = fmaf(a4.y, b4.x, acc[1][0]);
            acc[1][1] = fmaf(a4.y, b4.y, acc[1][1]);
            acc[1][2] = fmaf(a4.y, b4.z, acc[1][2]);
            acc[1][3] = fmaf(a4.y, b4.w, acc[1][3]);
            acc[2][0] = fmaf(a4.z, b4.x, acc[2][0]);
            acc[2][1] = fmaf(a4.z, b4.y, acc[2][1]);
            acc[2][2] = fmaf(a4.z, b4.z, acc[2][2]);
            acc[2][3] = fmaf(a4.z, b4.w, acc[2][3]);
            acc[3][0] = fmaf(a4.w, b4.x, acc[3][0]);
            acc[3][1] = fmaf(a4.w, b4.y, acc[3][1]);
            acc[3][2] = fmaf(a4.w, b4.z, acc[3][2]);
            acc[3][3] = fmaf(a4.w, b4.w, acc[3][3]);
        }
    }

#pragma unroll
    for (int i = 0; i < 4; ++i) {
        const int m = row0 + (ty << 2) + i;
        if (m >= M) continue;
#pragma unroll
        for (int j = 0; j < 4; ++j) {
            const int n = col0 + (tx << 2) + j;
            float v = acc[i][j];
            if (bias1) v += bias1[n];
            if (bias2) v += bias2[n];
            v *= post_scale;
            if (relu) v = fmaxf(v, 0.0f);
            if (out_mode == 0) {
                Cb[(long)m * ldc + n] = v;
            } else {
                const int bq = m / Tt_, tq = m - bq * Tt_;
                C[((long)tq * N + n) * Bb_ + bq] = v;
            }
        }
    }
}

// ---------------------------------------------------------------------------
// Embedding lookup: x[m][:] = emb[targets[m]][:]   (m = b*T + t), float4 wide
// ---------------------------------------------------------------------------
__global__ __launch_bounds__(256) void embed_kernel(
    const int* __restrict__ tgt, const float* __restrict__ emb,
    float* __restrict__ x)
{
    const int idx = blockIdx.x * 256 + threadIdx.x;   // float4 index
    if (idx >= Bb_ * Tt_ * (Hh_ / 4)) return;
    const int m = idx >> 7, c = idx & 127;
    const int token = tgt[m];
    *(float4*)(x + (long)m * Hh_ + (c << 2)) =
        *(const float4*)(emb + (long)token * Hh_ + (c << 2));
}

// ---------------------------------------------------------------------------
// LSTM recurrence (cooperative). 256 blocks x 512 threads.
// Block bi owns columns j = 2*bi, 2*bi+1.  Whh rows {q*512 + j} LDS-resident.
// Thread t: b = t&31, kq = (t>>5)&3 (K quarter), q = t>>7 (gate).
// h state broadcast via hsT[t][j][b]; one grid.sync per step.
// xgT layout: [T][4H][B].  hsT layout: [T][H][B].
// ---------------------------------------------------------------------------
__global__ __launch_bounds__(512) void lstm_kernel(
    const float* __restrict__ xgT, const float* __restrict__ Whh,
    float* __restrict__ hsT)
{
    extern __shared__ float lds[];
    float* w_lds = lds;                  // [8][512]
    float* hT    = lds + 4096;           // [512][32]
    float* p_lds = lds + 4096 + 16384;   // [4][2][2][32]

    const int t  = threadIdx.x;
    const int bi = blockIdx.x;
    const int b  = t & 31;
    const int kq = (t >> 5) & 3;
    const int q  = t >> 7;

    // load Whh slice: r = q2*2 + jl  ->  Whh[(q2*512 + 2*bi + jl)][k]
    for (int i = t; i < 4096; i += 512) {
        const int r = i >> 9, k = i & 511;
        w_lds[i] = Whh[((long)((r >> 1) * Hh_ + 2 * bi + (r & 1))) * Hh_ + k];
    }
    for (int i = t; i < 16384; i += 512) hT[i] = 0.0f;

    float creg = 0.0f;
    cg::grid_group grid = cg::this_grid();
    __syncthreads();

    const float* w0 = w_lds + (q * 2 + 0) * 512 + kq * 128;
    const float* w1 = w_lds + (q * 2 + 1) * 512 + kq * 128;

    for (int step = 0; step < Tt_; ++step) {
        float a00 = 0.f, a01 = 0.f, a10 = 0.f, a11 = 0.f;
#pragma unroll 4
        for (int k = 0; k < 128; k += 8) {
            const float4 wa = *(const float4*)(w0 + k);
            const float4 wb = *(const float4*)(w0 + k + 4);
            const float4 wc = *(const float4*)(w1 + k);
            const float4 wd = *(const float4*)(w1 + k + 4);
            const int kk = (kq * 128 + k) * 32 + b;
            const float h0 = hT[kk];       const float h1v = hT[kk + 32];
            const float h2 = hT[kk + 64];  const float h3 = hT[kk + 96];
            const float h4 = hT[kk + 128]; const float h5 = hT[kk + 160];
            const float h6 = hT[kk + 192]; const float h7 = hT[kk + 224];
            a00 = fmaf(wa.x, h0, a00); a00 = fmaf(wa.y, h1v, a00);
            a00 = fmaf(wa.z, h2, a00); a00 = fmaf(wa.w, h3, a00);
            a01 = fmaf(wb.x, h4, a01); a01 = fmaf(wb.y, h5, a01);
            a01 = fmaf(wb.z, h6, a01); a01 = fmaf(wb.w, h7, a01);
            a10 = fmaf(wc.x, h0, a10); a10 = fmaf(wc.y, h1v, a10);
            a10 = fmaf(wc.z, h2, a10); a10 = fmaf(wc.w, h3, a10);
            a11 = fmaf(wd.x, h4, a11); a11 = fmaf(wd.y, h5, a11);
            a11 = fmaf(wd.z, h6, a11); a11 = fmaf(wd.w, h7, a11);
        }
        float acc0 = a00 + a01;
        float acc1 = a10 + a11;
        acc0 += __shfl_xor(acc0, 32);
        acc1 += __shfl_xor(acc1, 32);
        if ((t & 32) == 0) {                 // kq-low == 0 lanes hold pair sums
            const int khi = (t >> 6) & 1;
            p_lds[((q * 2 + khi) * 2 + 0) * 32 + b] = acc0;
            p_lds[((q * 2 + khi) * 2 + 1) * 32 + b] = acc1;
        }
        __syncthreads();
        if (t < 64) {
            const int jl = t >> 5, bb = t & 31;
            const int j = 2 * bi + jl;
            const long xbase = (long)step * (4 * Hh_) * Bb_;
            float g0 = p_lds[((0 * 2 + 0) * 2 + jl) * 32 + bb] + p_lds[((0 * 2 + 1) * 2 + jl) * 32 + bb]
                     + xgT[xbase + (long)(0 * Hh_ + j) * Bb_ + bb];
            float g1 = p_lds[((1 * 2 + 0) * 2 + jl) * 32 + bb] + p_lds[((1 * 2 + 1) * 2 + jl) * 32 + bb]
                     + xgT[xbase + (long)(1 * Hh_ + j) * Bb_ + bb];
            float g2 = p_lds[((2 * 2 + 0) * 2 + jl) * 32 + bb] + p_lds[((2 * 2 + 1) * 2 + jl) * 32 + bb]
                     + xgT[xbase + (long)(2 * Hh_ + j) * Bb_ + bb];
            float g3 = p_lds[((3 * 2 + 0) * 2 + jl) * 32 + bb] + p_lds[((3 * 2 + 1) * 2 + jl) * 32 + bb]
                     + xgT[xbase + (long)(3 * Hh_ + j) * Bb_ + bb];
            const float si = 1.0f / (1.0f + expf(-g0));
            const float sf = 1.0f / (1.0f + expf(-g1));
            const float so = 1.0f / (1.0f + expf(-g3));
            creg = sf * creg + si * tanhf(g2);
            const float hv = so * tanhf(creg);
            hsT[((long)step * Hh_ + j) * Bb_ + bb] = hv;
        }
        grid.sync();
        const float* hsrc = hsT + (long)step * Hh_ * Bb_;
        for (int i = t; i < 4096; i += 512) {
            *(float4*)(hT + i * 4) = *(const float4*)(hsrc + i * 4);
        }
        __syncthreads();
    }
}

// ---------------------------------------------------------------------------
// Transpose [T][H][B] -> [B][T][H]
// ---------------------------------------------------------------------------
__global__ __launch_bounds__(256) void transpose_kernel(
    const float* __restrict__ in, float* __restrict__ out)
{
    __shared__ float tile[32][33];
    const int tq = blockIdx.y;
    const int j0 = blockIdx.x * 32;
    const int t = threadIdx.x;
    for (int i = t; i < 1024; i += 256) {
        const int j = i >> 5, b = i & 31;
        tile[j][b] = in[((long)tq * Hh_ + j0 + j) * Bb_ + b];
    }
    __syncthreads();
    for (int i = t; i < 1024; i += 256) {
        const int b = i >> 5, j = i & 31;
        out[((long)b * Tt_ + tq) * Hh_ + j0 + j] = tile[j][b];
    }
}

// ---------------------------------------------------------------------------
// Row softmax over S=512 (scale already folded into q). One block per row.
// ---------------------------------------------------------------------------
__global__ __launch_bounds__(256) void softmax_kernel(float* __restrict__ s)
{
    __shared__ float red[8];
    const long row = blockIdx.x;
    float* p = s + row * Ss_;
    const int t = threadIdx.x;
    float v0 = p[t], v1 = p[t + 256];
    float m = fmaxf(v0, v1);
    for (int off = 32; off; off >>= 1) m = fmaxf(m, __shfl_xor(m, off));
    if ((t & 63) == 0) red[t >> 6] = m;
    __syncthreads();
    m = fmaxf(fmaxf(red[0], red[1]), fmaxf(red[2], red[3]));
    const float e0 = expf(v0 - m), e1 = expf(v1 - m);
    float sm = e0 + e1;
    for (int off = 32; off; off >>= 1) sm += __shfl_xor(sm, off);
    if ((t & 63) == 0) red[4 + (t >> 6)] = sm;
    __syncthreads();
    const float inv = 1.0f / (red[4] + red[5] + red[6] + red[7]);
    p[t] = e0 * inv;
    p[t + 256] = e1 * inv;
}

// ---------------------------------------------------------------------------
// Concat: comb[m][0:512] = hs1[m], comb[m][512:1024] = attn_o[m]  (float4)
// ---------------------------------------------------------------------------
__global__ __launch_bounds__(256) void concat_kernel(
    const float* __restrict__ a, const float* __restrict__ bsrc,
    float* __restrict__ comb)
{
    const int idx = blockIdx.x * 256 + threadIdx.x;   // float4 index
    if (idx >= Bb_ * Tt_ * 256) return;
    const int m = idx >> 8, c = idx & 255;
    float4 v;
    if (c < 128) v = *(const float4*)(a + (long)m * Hh_ + (c << 2));
    else         v = *(const float4*)(bsrc + (long)m * Hh_ + ((c - 128) << 2));
    *(float4*)(comb + (long)m * 1024 + (c << 2)) = v;
}

// ---------------------------------------------------------------------------
static void gemm(hipStream_t s,
                 const float* A, int lda, long sAb, long sAh,
                 const float* B, int ldb, long sBb, long sBh, int transB,
                 float* C, int ldc, long sCb, long sCh,
                 int M, int N, int K, int NH, int Z,
                 const float* b1, const float* b2, int relu, float ps, int om)
{
    dim3 g(N / 64, (M + 63) / 64, Z);
    hipLaunchKernelGGL(gemm_kernel, g, dim3(256), 0, s,
                       A, lda, sAb, sAh, B, ldb, sBb, sBh, transB,
                       C, ldc, sCb, sCh, M, N, K, NH, b1, b2, relu, ps, om);
}

extern "C" void kernel_launch(void* const* d_in, const int* in_sizes, int n_in,
                              void* d_out, int out_size, void* d_ws, size_t ws_size,
                              hipStream_t stream)
{
    const float* enc_in  = (const float*)d_in[0];
    const int*   targets = (const int*)d_in[1];
    const float* emb     = (const float*)d_in[2];
    const float* Wih0    = (const float*)d_in[3];
    const float* Whh0    = (const float*)d_in[4];
    const float* bih0    = (const float*)d_in[5];
    const float* bhh0    = (const float*)d_in[6];
    const float* Wih1    = (const float*)d_in[7];
    const float* Whh1    = (const float*)d_in[8];
    const float* bih1    = (const float*)d_in[9];
    const float* bhh1    = (const float*)d_in[10];
    const float* attn_in_w  = (const float*)d_in[11];
    const float* attn_in_b  = (const float*)d_in[12];
    const float* attn_out_w = (const float*)d_in[13];
    const float* attn_out_b = (const float*)d_in[14];
    const float* encproj_w  = (const float*)d_in[15];
    const float* encproj_b  = (const float*)d_in[16];
    const float* out1_w     = (const float*)d_in[17];
    const float* out1_b     = (const float*)d_in[18];
    const float* out2_w     = (const float*)d_in[19];
    const float* out2_b     = (const float*)d_in[20];
    float* out = (float*)d_out;
    float* ws  = (float*)d_ws;

    // workspace layout (floats)
    const long SZ_A = 16384L * 512;       // 8,388,608
    float* enc   = ws;                    // region A (later reused)
    float* kbuf  = ws + SZ_A;             // region B
    float* vbuf  = ws + 2 * SZ_A;         // region C
    float* xbuf  = ws;                    // A reuse (enc dead after k/v)
    float* xgT   = ws + 1638400;          // A + x  ([T][4H][B] = 6,553,600)
    float* hsT0  = ws + 3 * SZ_A;                    // D  (1,638,400)
    float* hs0   = ws + 3 * SZ_A + 1 * 1638400L;     // E
    float* hsT1  = hsT0;                             // D reuse
    float* hs1   = ws + 3 * SZ_A + 2 * 1638400L;     // F (lstm_out)
    float* qbuf  = ws + 3 * SZ_A + 3 * 1638400L;     // G
    float* scores = ws;                              // A reuse (6,553,600)
    float* ctxb  = ws + 6553600;                     // A upper (1,638,400)
    float* attn_o = hsT1;                            // D reuse
    float* comb  = kbuf;                             // B reuse (3,276,800)
    float* h1    = kbuf + 3276800;                   // B upper

    const float qscale = 0.08838834764831845f;  // 1/sqrt(128)
    const size_t LSTM_LDS = (4096 + 16384 + 512) * sizeof(float);  // 84 KB
    (void)hipFuncSetAttribute((const void*)lstm_kernel,
                              hipFuncAttributeMaxDynamicSharedMemorySize,
                              (int)LSTM_LDS);

    // 1. enc = encoder_outputs @ encproj_w^T + b      [16384,512]
    gemm(stream, enc_in, Ee_, 0, 0, encproj_w, Ee_, 0, 0, 1,
         enc, Hh_, 0, 0, Bb_ * Ss_, Hh_, Ee_, 1, 1,
         encproj_b, nullptr, 0, 1.0f, 0);
    // 2. k = enc @ Wk^T + bk ;  3. v = enc @ Wv^T + bv
    gemm(stream, enc, Hh_, 0, 0, attn_in_w + Hh_ * Hh_, Hh_, 0, 0, 1,
         kbuf, Hh_, 0, 0, Bb_ * Ss_, Hh_, Hh_, 1, 1,
         attn_in_b + Hh_, nullptr, 0, 1.0f, 0);
    gemm(stream, enc, Hh_, 0, 0, attn_in_w + 2 * Hh_ * Hh_, Hh_, 0, 0, 1,
         vbuf, Hh_, 0, 0, Bb_ * Ss_, Hh_, Hh_, 1, 1,
         attn_in_b + 2 * Hh_, nullptr, 0, 1.0f, 0);
    // 4. embedding (overwrites enc region — enc no longer needed)
    hipLaunchKernelGGL(embed_kernel, dim3(1600), dim3(256), 0, stream,
                       targets, emb, xbuf);
    // 5. xg0 = x @ Wih0^T + bih0 + bhh0  -> xgT [T][4H][B]
    gemm(stream, xbuf, Hh_, 0, 0, Wih0, Hh_, 0, 0, 1,
         xgT, 0, 0, 0, Bb_ * Tt_, 4 * Hh_, Hh_, 1, 1,
         bih0, bhh0, 0, 1.0f, 1);
    // 6. LSTM layer 0
    {
        const float* a = xgT; const float* w = Whh0; float* o = hsT0;
        void* args[] = { (void*)&a, (void*)&w, (void*)&o };
        hipLaunchCooperativeKernel((const void*)lstm_kernel, dim3(256), dim3(512),
                                   args, (unsigned int)LSTM_LDS, stream);
    }
    // 7. transpose hsT0 -> hs0 [B][T][H]
    hipLaunchKernelGGL(transpose_kernel, dim3(16, 100), dim3(256), 0, stream, hsT0, hs0);
    // 8. xg1 = hs0 @ Wih1^T + biases -> xgT
    gemm(stream, hs0, Hh_, 0, 0, Wih1, Hh_, 0, 0, 1,
         xgT, 0, 0, 0, Bb_ * Tt_, 4 * Hh_, Hh_, 1, 1,
         bih1, bhh1, 0, 1.0f, 1);
    // 9. LSTM layer 1
    {
        const float* a = xgT; const float* w = Whh1; float* o = hsT1;
        void* args[] = { (void*)&a, (void*)&w, (void*)&o };
        hipLaunchCooperativeKernel((const void*)lstm_kernel, dim3(256), dim3(512),
                                   args, (unsigned int)LSTM_LDS, stream);
    }
    // 10. transpose hsT1 -> hs1
    hipLaunchKernelGGL(transpose_kernel, dim3(16, 100), dim3(256), 0, stream, hsT1, hs1);
    // 11. q = (hs1 @ Wq^T + bq) * 1/sqrt(HD)
    gemm(stream, hs1, Hh_, 0, 0, attn_in_w, Hh_, 0, 0, 1,
         qbuf, Hh_, 0, 0, Bb_ * Tt_, Hh_, Hh_, 1, 1,
         attn_in_b, nullptr, 0, qscale, 0);
    // 12. scores[b,h] = q[b,:,h,:] @ k[b,:,h,:]^T   (z = b*4+h)
    gemm(stream, qbuf, Hh_, (long)Tt_ * Hh_, HDd_,
         kbuf, Hh_, (long)Ss_ * Hh_, HDd_, 1,
         scores, Ss_, (long)NHh_ * Tt_ * Ss_, (long)Tt_ * Ss_,
         Tt_, Ss_, HDd_, NHh_, Bb_ * NHh_,
         nullptr, nullptr, 0, 1.0f, 0);
    // 13. softmax rows
    hipLaunchKernelGGL(softmax_kernel, dim3(Bb_ * NHh_ * Tt_), dim3(256), 0, stream, scores);
    // 14. ctx[b,h] = attn @ v[b,:,h,:]   (transB=0)
    gemm(stream, scores, Ss_, (long)NHh_ * Tt_ * Ss_, (long)Tt_ * Ss_,
         vbuf, Hh_, (long)Ss_ * Hh_, HDd_, 0,
         ctxb, Hh_, (long)Tt_ * Hh_, HDd_,
         Tt_, HDd_, Ss_, NHh_, Bb_ * NHh_,
         nullptr, nullptr, 0, 1.0f, 0);
    // 15. attn_out = ctx @ attn_out_w^T + b
    gemm(stream, ctxb, Hh_, 0, 0, attn_out_w, Hh_, 0, 0, 1,
         attn_o, Hh_, 0, 0, Bb_ * Tt_, Hh_, Hh_, 1, 1,
         attn_out_b, nullptr, 0, 1.0f, 0);
    // 16. combined = [hs1, attn_out]
    hipLaunchKernelGGL(concat_kernel, dim3(3200), dim3(256), 0, stream, hs1, attn_o, comb);
    // 17. h1 = relu(combined @ out1_w^T + b)
    gemm(stream, comb, 2 * Hh_, 0, 0, out1_w, 2 * Hh_, 0, 0, 1,
         h1, Hh_, 0, 0, Bb_ * Tt_, Hh_, 2 * Hh_, 1, 1,
         out1_b, nullptr, 1, 1.0f, 0);
    // 18. logits = h1 @ out2_w^T + b  -> d_out [3200][8192]
    gemm(stream, h1, Hh_, 0, 0, out2_w, Hh_, 0, 0, 1,
         out, Vv_, 0, 0, Bb_ * Tt_, Vv_, Hh_, 1, 1,
         out2_b, nullptr, 0, 1.0f, 0);
}

// Round 2
// 3977.694 us; speedup vs baseline: 1.9313x; 1.9313x over previous
//
#include <hip/hip_runtime.h>
#include <hip/hip_bf16.h>

// Problem dims
#define Bb_ 32
#define Tt_ 100
#define Ss_ 512
#define Ee_ 1024
#define Hh_ 512
#define Vv_ 8192
#define NHh_ 4
#define HDd_ 128

// ---------------------------------------------------------------------------
// Generic tiled fp32 GEMM: C = A @ op(B) + bias1 + bias2, optional relu/scale.
// A: [M][K] row-major (lda). B: transB=1 -> [N][K] (ldb); transB=0 -> [K][N].
// Batched via blockIdx.z: z -> (bz = z/NH, hz = z%NH).
// out_mode 0: normal row-major C; out_mode 1: xg scatter -> [T][4H][B]
// ---------------------------------------------------------------------------
__global__ __launch_bounds__(256) void gemm_kernel(
    const float* __restrict__ A, int lda, long sAb, long sAh,
    const float* __restrict__ B, int ldb, long sBb, long sBh, int transB,
    float* __restrict__ C, int ldc, long sCb, long sCh,
    int M, int N, int K, int NH,
    const float* __restrict__ bias1, const float* __restrict__ bias2,
    int relu, float post_scale, int out_mode)
{
    __shared__ float As[16][64];
    __shared__ float Bs[16][64];
    const int z = blockIdx.z;
    const int bz = z / NH, hz = z % NH;
    const float* Ab = A + (long)bz * sAb + (long)hz * sAh;
    const float* Bbp = B + (long)bz * sBb + (long)hz * sBh;
    float* Cb = C + (long)bz * sCb + (long)hz * sCh;

    const int row0 = blockIdx.y * 64, col0 = blockIdx.x * 64;
    const int t = threadIdx.x;
    const int ar = t >> 2, ac = (t & 3) << 2;
    const int ty = t >> 4, tx = t & 15;

    float acc[4][4] = {};

    for (int k0 = 0; k0 < K; k0 += 16) {
        int am = row0 + ar; if (am >= M) am = M - 1;
        const float4 av = *(const float4*)(Ab + (long)am * lda + k0 + ac);
        float4 bv;
        if (transB) {
            bv = *(const float4*)(Bbp + (long)(col0 + ar) * ldb + k0 + ac);
        } else {
            bv = *(const float4*)(Bbp + (long)(k0 + ty) * ldb + col0 + (tx << 2));
        }
        __syncthreads();
        As[ac + 0][ar] = av.x; As[ac + 1][ar] = av.y;
        As[ac + 2][ar] = av.z; As[ac + 3][ar] = av.w;
        if (transB) {
            Bs[ac + 0][ar] = bv.x; Bs[ac + 1][ar] = bv.y;
            Bs[ac + 2][ar] = bv.z; Bs[ac + 3][ar] = bv.w;
        } else {
            *(float4*)&Bs[ty][tx << 2] = bv;
        }
        __syncthreads();
#pragma unroll
        for (int kk = 0; kk < 16; ++kk) {
            const float4 a4 = *(const float4*)&As[kk][ty << 2];
            const float4 b4 = *(const float4*)&Bs[kk][tx << 2];
            acc[0][0] = fmaf(a4.x, b4.x, acc[0][0]);
            acc[0][1] = fmaf(a4.x, b4.y, acc[0][1]);
            acc[0][2] = fmaf(a4.x, b4.z, acc[0][2]);
            acc[0][3] = fmaf(a4.x, b4.w, acc[0][3]);
            acc[1][0] = fmaf(a4.y, b4.x, acc[1][0]);
            acc[1][1] = fmaf(a4.y, b4.y, acc[1][1]);
            acc[1][2] = fmaf(a4.y, b4.z, acc[1][2]);
            acc[1][3] = fmaf(a4.y, b4.w, acc[1][3]);
            acc[2][0] = fmaf(a4.z, b4.x, acc[2][0]);
            acc[2][1] = fmaf(a4.z, b4.y, acc[2][1]);
            acc[2][2] = fmaf(a4.z, b4.z, acc[2][2]);
            acc[2][3] = fmaf(a4.z, b4.w, acc[2][3]);
            acc[3][0] = fmaf(a4.w, b4.x, acc[3][0]);
            acc[3][1] = fmaf(a4.w, b4.y, acc[3][1]);
            acc[3][2] = fmaf(a4.w, b4.z, acc[3][2]);
            acc[3][3] = fmaf(a4.w, b4.w, acc[3][3]);
        }
    }

#pragma unroll
    for (int i = 0; i < 4; ++i) {
        const int m = row0 + (ty << 2) + i;
        if (m >= M) continue;
#pragma unroll
        for (int j = 0; j < 4; ++j) {
            const int n = col0 + (tx << 2) + j;
            float v = acc[i][j];
            if (bias1) v += bias1[n];
            if (bias2) v += bias2[n];
            v *= post_scale;
            if (relu) v = fmaxf(v, 0.0f);
            if (out_mode == 0) {
                Cb[(long)m * ldc + n] = v;
            } else {
                const int bq = m / Tt_, tq = m - bq * Tt_;
                C[((long)tq * N + n) * Bb_ + bq] = v;
            }
        }
    }
}

// ---------------------------------------------------------------------------
// Embedding lookup: x[m][:] = emb[targets[m]][:]   (m = b*T + t), float4 wide
// ---------------------------------------------------------------------------
__global__ __launch_bounds__(256) void embed_kernel(
    const int* __restrict__ tgt, const float* __restrict__ emb,
    float* __restrict__ x)
{
    const int idx = blockIdx.x * 256 + threadIdx.x;   // float4 index
    if (idx >= Bb_ * Tt_ * (Hh_ / 4)) return;
    const int m = idx >> 7, c = idx & 127;
    const int token = tgt[m];
    *(float4*)(x + (long)m * Hh_ + (c << 2)) =
        *(const float4*)(emb + (long)token * Hh_ + (c << 2));
}

// ---------------------------------------------------------------------------
// LSTM recurrence. 256 blocks x 512 threads, co-resident (cooperative launch).
// Block bi owns columns j = 2*bi, 2*bi+1.  Whh rows LDS-resident.
// Cross-block h exchange via LLC (agent-scope relaxed atomics, cache-bypass).
// Custom flag barrier: flags[bid] = step+1 (monotone); poll 256 flags.
// NO grid.sync / threadfence -> no per-step L2 writeback+invalidate.
// xgT layout: [T][4H][B].  hsT layout: [T][H][B].
// ---------------------------------------------------------------------------
__global__ __launch_bounds__(512) void lstm_kernel(
    const float* __restrict__ xgT, const float* __restrict__ Whh,
    float* __restrict__ hsT, int* __restrict__ flags)
{
    extern __shared__ float lds[];
    float* w_lds = lds;                  // [8][512]
    float* hT    = lds + 4096;           // [512][32]
    float* p_lds = lds + 4096 + 16384;   // [4][2][2][32]

    const int t  = threadIdx.x;
    const int bi = blockIdx.x;
    const int b  = t & 31;
    const int kq = (t >> 5) & 3;
    const int q  = t >> 7;

    // load Whh slice: r = q2*2 + jl  ->  Whh[(q2*512 + 2*bi + jl)][k]
    for (int i = t; i < 4096; i += 512) {
        const int r = i >> 9, k = i & 511;
        w_lds[i] = Whh[((long)((r >> 1) * Hh_ + 2 * bi + (r & 1))) * Hh_ + k];
    }
    for (int i = t; i < 16384; i += 512) hT[i] = 0.0f;

    float creg = 0.0f;
    __syncthreads();

    const float* w0 = w_lds + (q * 2 + 0) * 512 + kq * 128;
    const float* w1 = w_lds + (q * 2 + 1) * 512 + kq * 128;

    for (int step = 0; step < Tt_; ++step) {
        float a00 = 0.f, a01 = 0.f, a10 = 0.f, a11 = 0.f;
#pragma unroll 4
        for (int k = 0; k < 128; k += 8) {
            const float4 wa = *(const float4*)(w0 + k);
            const float4 wb = *(const float4*)(w0 + k + 4);
            const float4 wc = *(const float4*)(w1 + k);
            const float4 wd = *(const float4*)(w1 + k + 4);
            const int kk = (kq * 128 + k) * 32 + b;
            const float h0 = hT[kk];       const float h1v = hT[kk + 32];
            const float h2 = hT[kk + 64];  const float h3 = hT[kk + 96];
            const float h4 = hT[kk + 128]; const float h5 = hT[kk + 160];
            const float h6 = hT[kk + 192]; const float h7 = hT[kk + 224];
            a00 = fmaf(wa.x, h0, a00); a00 = fmaf(wa.y, h1v, a00);
            a00 = fmaf(wa.z, h2, a00); a00 = fmaf(wa.w, h3, a00);
            a01 = fmaf(wb.x, h4, a01); a01 = fmaf(wb.y, h5, a01);
            a01 = fmaf(wb.z, h6, a01); a01 = fmaf(wb.w, h7, a01);
            a10 = fmaf(wc.x, h0, a10); a10 = fmaf(wc.y, h1v, a10);
            a10 = fmaf(wc.z, h2, a10); a10 = fmaf(wc.w, h3, a10);
            a11 = fmaf(wd.x, h4, a11); a11 = fmaf(wd.y, h5, a11);
            a11 = fmaf(wd.z, h6, a11); a11 = fmaf(wd.w, h7, a11);
        }
        float acc0 = a00 + a01;
        float acc1 = a10 + a11;
        acc0 += __shfl_xor(acc0, 32);
        acc1 += __shfl_xor(acc1, 32);
        if ((t & 32) == 0) {                 // kq-low == 0 lanes hold pair sums
            const int khi = (t >> 6) & 1;
            p_lds[((q * 2 + khi) * 2 + 0) * 32 + b] = acc0;
            p_lds[((q * 2 + khi) * 2 + 1) * 32 + b] = acc1;
        }
        __syncthreads();
        if (t < 64) {
            const int jl = t >> 5, bb = t & 31;
            const int j = 2 * bi + jl;
            const long xbase = (long)step * (4 * Hh_) * Bb_;
            float g0 = p_lds[((0 * 2 + 0) * 2 + jl) * 32 + bb] + p_lds[((0 * 2 + 1) * 2 + jl) * 32 + bb]
                     + xgT[xbase + (long)(0 * Hh_ + j) * Bb_ + bb];
            float g1 = p_lds[((1 * 2 + 0) * 2 + jl) * 32 + bb] + p_lds[((1 * 2 + 1) * 2 + jl) * 32 + bb]
                     + xgT[xbase + (long)(1 * Hh_ + j) * Bb_ + bb];
            float g2 = p_lds[((2 * 2 + 0) * 2 + jl) * 32 + bb] + p_lds[((2 * 2 + 1) * 2 + jl) * 32 + bb]
                     + xgT[xbase + (long)(2 * Hh_ + j) * Bb_ + bb];
            float g3 = p_lds[((3 * 2 + 0) * 2 + jl) * 32 + bb] + p_lds[((3 * 2 + 1) * 2 + jl) * 32 + bb]
                     + xgT[xbase + (long)(3 * Hh_ + j) * Bb_ + bb];
            const float si = 1.0f / (1.0f + expf(-g0));
            const float sf = 1.0f / (1.0f + expf(-g1));
            const float so = 1.0f / (1.0f + expf(-g3));
            creg = sf * creg + si * tanhf(g2);
            const float hv = so * tanhf(creg);
            // cache-bypassing store -> LLC (device-visible without L2 flush)
            __hip_atomic_store(&hsT[((long)step * Hh_ + j) * Bb_ + bb], hv,
                               __ATOMIC_RELAXED, __HIP_MEMORY_SCOPE_AGENT);
        }
        // __syncthreads drains each wave's vmcnt -> all h stores are complete
        // (acked at LLC) before any thread proceeds to signal.
        __syncthreads();
        if (t == 0) {
            __hip_atomic_store(&flags[bi], step + 1,
                               __ATOMIC_RELAXED, __HIP_MEMORY_SCOPE_AGENT);
        }
        // spin until all 256 blocks have published step+1 (flags are monotone,
        // per-step h buffers are disjoint -> no ABA race)
        for (;;) {
            int f = (t < 256)
                  ? __hip_atomic_load(&flags[t], __ATOMIC_RELAXED, __HIP_MEMORY_SCOPE_AGENT)
                  : 0x7fffffff;
            if (__syncthreads_count(f <= step) == 0) break;
        }
        // pull fresh h ([512][32] = 64KB) into LDS via cache-bypassing loads
        const unsigned long long* hsrc =
            (const unsigned long long*)(hsT + (long)step * Hh_ * Bb_);
        unsigned long long* hdst = (unsigned long long*)hT;
#pragma unroll
        for (int i = 0; i < 16; ++i) {
            hdst[t + i * 512] = __hip_atomic_load(hsrc + t + i * 512,
                                                  __ATOMIC_RELAXED, __HIP_MEMORY_SCOPE_AGENT);
        }
        __syncthreads();
    }
}

// ---------------------------------------------------------------------------
// Transpose [T][H][B] -> [B][T][H]
// ---------------------------------------------------------------------------
__global__ __launch_bounds__(256) void transpose_kernel(
    const float* __restrict__ in, float* __restrict__ out)
{
    __shared__ float tile[32][33];
    const int tq = blockIdx.y;
    const int j0 = blockIdx.x * 32;
    const int t = threadIdx.x;
    for (int i = t; i < 1024; i += 256) {
        const int j = i >> 5, b = i & 31;
        tile[j][b] = in[((long)tq * Hh_ + j0 + j) * Bb_ + b];
    }
    __syncthreads();
    for (int i = t; i < 1024; i += 256) {
        const int b = i >> 5, j = i & 31;
        out[((long)b * Tt_ + tq) * Hh_ + j0 + j] = tile[j][b];
    }
}

// ---------------------------------------------------------------------------
// Row softmax over S=512 (scale already folded into q). One block per row.
// ---------------------------------------------------------------------------
__global__ __launch_bounds__(256) void softmax_kernel(float* __restrict__ s)
{
    __shared__ float red[8];
    const long row = blockIdx.x;
    float* p = s + row * Ss_;
    const int t = threadIdx.x;
    float v0 = p[t], v1 = p[t + 256];
    float m = fmaxf(v0, v1);
    for (int off = 32; off; off >>= 1) m = fmaxf(m, __shfl_xor(m, off));
    if ((t & 63) == 0) red[t >> 6] = m;
    __syncthreads();
    m = fmaxf(fmaxf(red[0], red[1]), fmaxf(red[2], red[3]));
    const float e0 = expf(v0 - m), e1 = expf(v1 - m);
    float sm = e0 + e1;
    for (int off = 32; off; off >>= 1) sm += __shfl_xor(sm, off);
    if ((t & 63) == 0) red[4 + (t >> 6)] = sm;
    __syncthreads();
    const float inv = 1.0f / (red[4] + red[5] + red[6] + red[7]);
    p[t] = e0 * inv;
    p[t + 256] = e1 * inv;
}

// ---------------------------------------------------------------------------
// Concat: comb[m][0:512] = hs1[m], comb[m][512:1024] = attn_o[m]  (float4)
// ---------------------------------------------------------------------------
__global__ __launch_bounds__(256) void concat_kernel(
    const float* __restrict__ a, const float* __restrict__ bsrc,
    float* __restrict__ comb)
{
    const int idx = blockIdx.x * 256 + threadIdx.x;   // float4 index
    if (idx >= Bb_ * Tt_ * 256) return;
    const int m = idx >> 8, c = idx & 255;
    float4 v;
    if (c < 128) v = *(const float4*)(a + (long)m * Hh_ + (c << 2));
    else         v = *(const float4*)(bsrc + (long)m * Hh_ + ((c - 128) << 2));
    *(float4*)(comb + (long)m * 1024 + (c << 2)) = v;
}

// ---------------------------------------------------------------------------
static void gemm(hipStream_t s,
                 const float* A, int lda, long sAb, long sAh,
                 const float* B, int ldb, long sBb, long sBh, int transB,
                 float* C, int ldc, long sCb, long sCh,
                 int M, int N, int K, int NH, int Z,
                 const float* b1, const float* b2, int relu, float ps, int om)
{
    dim3 g(N / 64, (M + 63) / 64, Z);
    hipLaunchKernelGGL(gemm_kernel, g, dim3(256), 0, s,
                       A, lda, sAb, sAh, B, ldb, sBb, sBh, transB,
                       C, ldc, sCb, sCh, M, N, K, NH, b1, b2, relu, ps, om);
}

extern "C" void kernel_launch(void* const* d_in, const int* in_sizes, int n_in,
                              void* d_out, int out_size, void* d_ws, size_t ws_size,
                              hipStream_t stream)
{
    const float* enc_in  = (const float*)d_in[0];
    const int*   targets = (const int*)d_in[1];
    const float* emb     = (const float*)d_in[2];
    const float* Wih0    = (const float*)d_in[3];
    const float* Whh0    = (const float*)d_in[4];
    const float* bih0    = (const float*)d_in[5];
    const float* bhh0    = (const float*)d_in[6];
    const float* Wih1    = (const float*)d_in[7];
    const float* Whh1    = (const float*)d_in[8];
    const float* bih1    = (const float*)d_in[9];
    const float* bhh1    = (const float*)d_in[10];
    const float* attn_in_w  = (const float*)d_in[11];
    const float* attn_in_b  = (const float*)d_in[12];
    const float* attn_out_w = (const float*)d_in[13];
    const float* attn_out_b = (const float*)d_in[14];
    const float* encproj_w  = (const float*)d_in[15];
    const float* encproj_b  = (const float*)d_in[16];
    const float* out1_w     = (const float*)d_in[17];
    const float* out1_b     = (const float*)d_in[18];
    const float* out2_w     = (const float*)d_in[19];
    const float* out2_b     = (const float*)d_in[20];
    float* out = (float*)d_out;
    float* ws  = (float*)d_ws;

    // workspace layout (floats)
    const long SZ_A = 16384L * 512;       // 8,388,608
    float* enc   = ws;                    // region A (later reused)
    float* kbuf  = ws + SZ_A;             // region B
    float* vbuf  = ws + 2 * SZ_A;         // region C
    float* xbuf  = ws;                    // A reuse (enc dead after k/v)
    float* xgT   = ws + 1638400;          // A + x  ([T][4H][B] = 6,553,600)
    float* hsT0  = ws + 3 * SZ_A;                    // D  (1,638,400)
    float* hs0   = ws + 3 * SZ_A + 1 * 1638400L;     // E
    float* hsT1  = hsT0;                             // D reuse
    float* hs1   = ws + 3 * SZ_A + 2 * 1638400L;     // F (lstm_out)
    float* qbuf  = ws + 3 * SZ_A + 3 * 1638400L;     // G
    float* scores = ws;                              // A reuse (6,553,600)
    float* ctxb  = ws + 6553600;                     // A upper (1,638,400)
    float* attn_o = hsT1;                            // D reuse
    float* comb  = kbuf;                             // B reuse (3,276,800)
    float* h1    = kbuf + 3276800;                   // B upper
    int*   flags0 = (int*)(ws + 3 * SZ_A + 4 * 1638400L);  // 256 ints
    int*   flags1 = flags0 + 256;                          // 256 ints

    const float qscale = 0.08838834764831845f;  // 1/sqrt(128)
    const size_t LSTM_LDS = (4096 + 16384 + 512) * sizeof(float);  // 84 KB
    (void)hipFuncSetAttribute((const void*)lstm_kernel,
                              hipFuncAttributeMaxDynamicSharedMemorySize,
                              (int)LSTM_LDS);

    // zero both flag arrays (ws is poisoned 0xAA before every launch)
    (void)hipMemsetAsync(flags0, 0, 512 * sizeof(int), stream);

    // 1. enc = encoder_outputs @ encproj_w^T + b      [16384,512]
    gemm(stream, enc_in, Ee_, 0, 0, encproj_w, Ee_, 0, 0, 1,
         enc, Hh_, 0, 0, Bb_ * Ss_, Hh_, Ee_, 1, 1,
         encproj_b, nullptr, 0, 1.0f, 0);
    // 2. k = enc @ Wk^T + bk ;  3. v = enc @ Wv^T + bv
    gemm(stream, enc, Hh_, 0, 0, attn_in_w + Hh_ * Hh_, Hh_, 0, 0, 1,
         kbuf, Hh_, 0, 0, Bb_ * Ss_, Hh_, Hh_, 1, 1,
         attn_in_b + Hh_, nullptr, 0, 1.0f, 0);
    gemm(stream, enc, Hh_, 0, 0, attn_in_w + 2 * Hh_ * Hh_, Hh_, 0, 0, 1,
         vbuf, Hh_, 0, 0, Bb_ * Ss_, Hh_, Hh_, 1, 1,
         attn_in_b + 2 * Hh_, nullptr, 0, 1.0f, 0);
    // 4. embedding (overwrites enc region — enc no longer needed)
    hipLaunchKernelGGL(embed_kernel, dim3(1600), dim3(256), 0, stream,
                       targets, emb, xbuf);
    // 5. xg0 = x @ Wih0^T + bih0 + bhh0  -> xgT [T][4H][B]
    gemm(stream, xbuf, Hh_, 0, 0, Wih0, Hh_, 0, 0, 1,
         xgT, 0, 0, 0, Bb_ * Tt_, 4 * Hh_, Hh_, 1, 1,
         bih0, bhh0, 0, 1.0f, 1);
    // 6. LSTM layer 0
    {
        const float* a = xgT; const float* w = Whh0; float* o = hsT0; int* f = flags0;
        void* args[] = { (void*)&a, (void*)&w, (void*)&o, (void*)&f };
        hipLaunchCooperativeKernel((const void*)lstm_kernel, dim3(256), dim3(512),
                                   args, (unsigned int)LSTM_LDS, stream);
    }
    // 7. transpose hsT0 -> hs0 [B][T][H]
    hipLaunchKernelGGL(transpose_kernel, dim3(16, 100), dim3(256), 0, stream, hsT0, hs0);
    // 8. xg1 = hs0 @ Wih1^T + biases -> xgT
    gemm(stream, hs0, Hh_, 0, 0, Wih1, Hh_, 0, 0, 1,
         xgT, 0, 0, 0, Bb_ * Tt_, 4 * Hh_, Hh_, 1, 1,
         bih1, bhh1, 0, 1.0f, 1);
    // 9. LSTM layer 1
    {
        const float* a = xgT; const float* w = Whh1; float* o = hsT1; int* f = flags1;
        void* args[] = { (void*)&a, (void*)&w, (void*)&o, (void*)&f };
        hipLaunchCooperativeKernel((const void*)lstm_kernel, dim3(256), dim3(512),
                                   args, (unsigned int)LSTM_LDS, stream);
    }
    // 10. transpose hsT1 -> hs1
    hipLaunchKernelGGL(transpose_kernel, dim3(16, 100), dim3(256), 0, stream, hsT1, hs1);
    // 11. q = (hs1 @ Wq^T + bq) * 1/sqrt(HD)
    gemm(stream, hs1, Hh_, 0, 0, attn_in_w, Hh_, 0, 0, 1,
         qbuf, Hh_, 0, 0, Bb_ * Tt_, Hh_, Hh_, 1, 1,
         attn_in_b, nullptr, 0, qscale, 0);
    // 12. scores[b,h] = q[b,:,h,:] @ k[b,:,h,:]^T   (z = b*4+h)
    gemm(stream, qbuf, Hh_, (long)Tt_ * Hh_, HDd_,
         kbuf, Hh_, (long)Ss_ * Hh_, HDd_, 1,
         scores, Ss_, (long)NHh_ * Tt_ * Ss_, (long)Tt_ * Ss_,
         Tt_, Ss_, HDd_, NHh_, Bb_ * NHh_,
         nullptr, nullptr, 0, 1.0f, 0);
    // 13. softmax rows
    hipLaunchKernelGGL(softmax_kernel, dim3(Bb_ * NHh_ * Tt_), dim3(256), 0, stream, scores);
    // 14. ctx[b,h] = attn @ v[b,:,h,:]   (transB=0)
    gemm(stream, scores, Ss_, (long)NHh_ * Tt_ * Ss_, (long)Tt_ * Ss_,
         vbuf, Hh_, (long)Ss_ * Hh_, HDd_, 0,
         ctxb, Hh_, (long)Tt_ * Hh_, HDd_,
         Tt_, HDd_, Ss_, NHh_, Bb_ * NHh_,
         nullptr, nullptr, 0, 1.0f, 0);
    // 15. attn_out = ctx @ attn_out_w^T + b
    gemm(stream, ctxb, Hh_, 0, 0, attn_out_w, Hh_, 0, 0, 1,
         attn_o, Hh_, 0, 0, Bb_ * Tt_, Hh_, Hh_, 1, 1,
         attn_out_b, nullptr, 0, 1.0f, 0);
    // 16. combined = [hs1, attn_out]
    hipLaunchKernelGGL(concat_kernel, dim3(3200), dim3(256), 0, stream, hs1, attn_o, comb);
    // 17. h1 = relu(combined @ out1_w^T + b)
    gemm(stream, comb, 2 * Hh_, 0, 0, out1_w, 2 * Hh_, 0, 0, 1,
         h1, Hh_, 0, 0, Bb_ * Tt_, Hh_, 2 * Hh_, 1, 1,
         out1_b, nullptr, 1, 1.0f, 0);
    // 18. logits = h1 @ out2_w^T + b  -> d_out [3200][8192]
    gemm(stream, h1, Hh_, 0, 0, out2_w, Hh_, 0, 0, 1,
         out, Vv_, 0, 0, Bb_ * Tt_, Vv_, Hh_, 1, 1,
         out2_b, nullptr, 0, 1.0f, 0);
}

// Round 3
// 3416.498 us; speedup vs baseline: 2.2485x; 1.1643x over previous
//
#include <hip/hip_runtime.h>
#include <hip/hip_bf16.h>

// Problem dims
#define Bb_ 32
#define Tt_ 100
#define Ss_ 512
#define Ee_ 1024
#define Hh_ 512
#define Vv_ 8192
#define NHh_ 4
#define HDd_ 128

// ---------------------------------------------------------------------------
// Tiled fp32 GEMM, 128x64 tile, 8x4 microtile. C = A @ op(B) + b1 + b2.
// A: [M][K] (lda). transB=1 -> B [N][K]; transB=0 -> B [K][N].
// Batched via blockIdx.z -> (bz=z/NH, hz=z%NH).
// out_mode 0: row-major C; out_mode 1: xg scatter -> [T][4H][B]
// ---------------------------------------------------------------------------
__global__ __launch_bounds__(256) void gemm_kernel(
    const float* __restrict__ A, int lda, long sAb, long sAh,
    const float* __restrict__ B, int ldb, long sBb, long sBh, int transB,
    float* __restrict__ C, int ldc, long sCb, long sCh,
    int M, int N, int K, int NH,
    const float* __restrict__ bias1, const float* __restrict__ bias2,
    int relu, float post_scale, int out_mode)
{
    __shared__ float As[16][128];
    __shared__ float Bs[16][64];
    const int z = blockIdx.z;
    const int bz = z / NH, hz = z % NH;
    const float* Ab = A + (long)bz * sAb + (long)hz * sAh;
    const float* Bbp = B + (long)bz * sBb + (long)hz * sBh;
    float* Cb = C + (long)bz * sCb + (long)hz * sCh;

    const int row0 = blockIdx.y * 128, col0 = blockIdx.x * 64;
    const int t = threadIdx.x;
    const int ar = t >> 1, ac = (t & 1) * 8;      // A loader
    const int bc = t >> 2, bk = (t & 3) * 4;      // B loader (transB=1)
    const int brow = t >> 4, bcol = (t & 15) * 4; // B loader (transB=0)
    const int ty = t >> 4, tx = t & 15;           // compute mapping

    float acc[8][4] = {};

    for (int k0 = 0; k0 < K; k0 += 16) {
        int am = row0 + ar; if (am >= M) am = M - 1;
        const float4 av0 = *(const float4*)(Ab + (long)am * lda + k0 + ac);
        const float4 av1 = *(const float4*)(Ab + (long)am * lda + k0 + ac + 4);
        float4 bv;
        if (transB) bv = *(const float4*)(Bbp + (long)(col0 + bc) * ldb + k0 + bk);
        else        bv = *(const float4*)(Bbp + (long)(k0 + brow) * ldb + col0 + bcol);
        __syncthreads();
        As[ac + 0][ar] = av0.x; As[ac + 1][ar] = av0.y;
        As[ac + 2][ar] = av0.z; As[ac + 3][ar] = av0.w;
        As[ac + 4][ar] = av1.x; As[ac + 5][ar] = av1.y;
        As[ac + 6][ar] = av1.z; As[ac + 7][ar] = av1.w;
        if (transB) {
            Bs[bk + 0][bc] = bv.x; Bs[bk + 1][bc] = bv.y;
            Bs[bk + 2][bc] = bv.z; Bs[bk + 3][bc] = bv.w;
        } else {
            *(float4*)&Bs[brow][bcol] = bv;
        }
        __syncthreads();
#pragma unroll
        for (int kk = 0; kk < 16; ++kk) {
            const float4 a4  = *(const float4*)&As[kk][ty * 8];
            const float4 a4b = *(const float4*)&As[kk][ty * 8 + 4];
            const float4 b4  = *(const float4*)&Bs[kk][tx * 4];
            const float af[8] = {a4.x, a4.y, a4.z, a4.w, a4b.x, a4b.y, a4b.z, a4b.w};
            const float bf[4] = {b4.x, b4.y, b4.z, b4.w};
#pragma unroll
            for (int i = 0; i < 8; ++i)
#pragma unroll
                for (int j = 0; j < 4; ++j)
                    acc[i][j] = fmaf(af[i], bf[j], acc[i][j]);
        }
    }

#pragma unroll
    for (int i = 0; i < 8; ++i) {
        const int m = row0 + ty * 8 + i;
        if (m >= M) continue;
#pragma unroll
        for (int j = 0; j < 4; ++j) {
            const int n = col0 + tx * 4 + j;
            float v = acc[i][j];
            if (bias1) v += bias1[n];
            if (bias2) v += bias2[n];
            v *= post_scale;
            if (relu) v = fmaxf(v, 0.0f);
            if (out_mode == 0) {
                Cb[(long)m * ldc + n] = v;
            } else {
                const int bq = m / Tt_, tq = m - bq * Tt_;
                C[((long)tq * N + n) * Bb_ + bq] = v;
            }
        }
    }
}

// ---------------------------------------------------------------------------
// Embedding lookup: x[m][:] = emb[targets[m]][:]
// ---------------------------------------------------------------------------
__global__ __launch_bounds__(256) void embed_kernel(
    const int* __restrict__ tgt, const float* __restrict__ emb,
    float* __restrict__ x)
{
    const int idx = blockIdx.x * 256 + threadIdx.x;   // float4 index
    if (idx >= Bb_ * Tt_ * (Hh_ / 4)) return;
    const int m = idx >> 7, c = idx & 127;
    const int token = tgt[m];
    *(float4*)(x + (long)m * Hh_ + (c << 2)) =
        *(const float4*)(emb + (long)token * Hh_ + (c << 2));
}

// ---------------------------------------------------------------------------
// LSTM recurrence v3. 128 blocks x 512 threads, co-resident.
// Block bi owns 4 columns j = 4*bi+jl. Whh rows (16) LDS-resident (32 KB).
// Thread t: b=t&31, kq=(t>>5)&3 (K quarter), q=t>>7 (gate). 4 col-accums.
// h publish: agent-scope (LLC) stores; flags[128] monotone, relaxed polls.
// h pull: NORMAL CACHED float4 loads — hsT[step] addresses are fresh each
// step (never previously cached by this block: producers bypass L2, region
// untouched by earlier dispatches, L1/L2 invalidated at dispatch start), so
// a post-flag cached read can only miss to LLC which holds fresh data.
// ---------------------------------------------------------------------------
__global__ __launch_bounds__(512) void lstm_kernel(
    const float* __restrict__ xgT, const float* __restrict__ Whh,
    float* __restrict__ hsT, int* __restrict__ flags)
{
    extern __shared__ float lds[];
    float* w_lds = lds;                   // [16][512] = 8192
    float* hT    = lds + 8192;            // [512][32] = 16384
    float* p_lds = lds + 8192 + 16384;    // [16][2][32] = 1024

    const int t  = threadIdx.x;
    const int bi = blockIdx.x;            // 0..127
    const int b  = t & 31;
    const int kq = (t >> 5) & 3;
    const int q  = t >> 7;

    // Whh rows: lds row r = q*4+jl  <-  global row q*512 + 4*bi + jl
    for (int i = t; i < 8192; i += 512) {
        const int r = i >> 9, k = i & 511;
        w_lds[i] = Whh[((long)((r >> 2) * Hh_ + 4 * bi + (r & 3))) * Hh_ + k];
    }
    for (int i = t; i < 16384; i += 512) hT[i] = 0.0f;

    float creg = 0.0f;
    __syncthreads();

    const float* wb0 = w_lds + (q * 4 + 0) * 512 + kq * 128;
    const float* wb1 = w_lds + (q * 4 + 1) * 512 + kq * 128;
    const float* wb2 = w_lds + (q * 4 + 2) * 512 + kq * 128;
    const float* wb3 = w_lds + (q * 4 + 3) * 512 + kq * 128;

    for (int step = 0; step < Tt_; ++step) {
        // xg prefetch (independent of h; hides L2/LLC latency under compute)
        float xr0 = 0.f, xr1 = 0.f, xr2 = 0.f, xr3 = 0.f;
        if (t < 128) {
            const int jl = t >> 5;
            const long xb = (long)step * (4 * Hh_) * Bb_
                          + (long)(4 * bi + jl) * Bb_ + (t & 31);
            xr0 = xgT[xb];
            xr1 = xgT[xb + 512 * Bb_];
            xr2 = xgT[xb + 1024 * Bb_];
            xr3 = xgT[xb + 1536 * Bb_];
        }
        float a0 = 0.f, a1 = 0.f, a2 = 0.f, a3 = 0.f;
#pragma unroll 4
        for (int k = 0; k < 128; k += 8) {
            const float4 w00 = *(const float4*)(wb0 + k);
            const float4 w01 = *(const float4*)(wb0 + k + 4);
            const float4 w10 = *(const float4*)(wb1 + k);
            const float4 w11 = *(const float4*)(wb1 + k + 4);
            const float4 w20 = *(const float4*)(wb2 + k);
            const float4 w21 = *(const float4*)(wb2 + k + 4);
            const float4 w30 = *(const float4*)(wb3 + k);
            const float4 w31 = *(const float4*)(wb3 + k + 4);
            const int kk = (kq * 128 + k) * 32 + b;
            const float h0 = hT[kk];       const float h1v = hT[kk + 32];
            const float h2 = hT[kk + 64];  const float h3 = hT[kk + 96];
            const float h4 = hT[kk + 128]; const float h5 = hT[kk + 160];
            const float h6 = hT[kk + 192]; const float h7 = hT[kk + 224];
            a0 = fmaf(w00.x, h0, a0); a0 = fmaf(w00.y, h1v, a0);
            a0 = fmaf(w00.z, h2, a0); a0 = fmaf(w00.w, h3, a0);
            a0 = fmaf(w01.x, h4, a0); a0 = fmaf(w01.y, h5, a0);
            a0 = fmaf(w01.z, h6, a0); a0 = fmaf(w01.w, h7, a0);
            a1 = fmaf(w10.x, h0, a1); a1 = fmaf(w10.y, h1v, a1);
            a1 = fmaf(w10.z, h2, a1); a1 = fmaf(w10.w, h3, a1);
            a1 = fmaf(w11.x, h4, a1); a1 = fmaf(w11.y, h5, a1);
            a1 = fmaf(w11.z, h6, a1); a1 = fmaf(w11.w, h7, a1);
            a2 = fmaf(w20.x, h0, a2); a2 = fmaf(w20.y, h1v, a2);
            a2 = fmaf(w20.z, h2, a2); a2 = fmaf(w20.w, h3, a2);
            a2 = fmaf(w21.x, h4, a2); a2 = fmaf(w21.y, h5, a2);
            a2 = fmaf(w21.z, h6, a2); a2 = fmaf(w21.w, h7, a2);
            a3 = fmaf(w30.x, h0, a3); a3 = fmaf(w30.y, h1v, a3);
            a3 = fmaf(w30.z, h2, a3); a3 = fmaf(w30.w, h3, a3);
            a3 = fmaf(w31.x, h4, a3); a3 = fmaf(w31.y, h5, a3);
            a3 = fmaf(w31.z, h6, a3); a3 = fmaf(w31.w, h7, a3);
        }
        a0 += __shfl_xor(a0, 32);
        a1 += __shfl_xor(a1, 32);
        a2 += __shfl_xor(a2, 32);
        a3 += __shfl_xor(a3, 32);
        if ((t & 32) == 0) {                 // kq even lanes hold pair sums
            const int khi = (t >> 6) & 1;
            p_lds[((q * 4 + 0) * 2 + khi) * 32 + b] = a0;
            p_lds[((q * 4 + 1) * 2 + khi) * 32 + b] = a1;
            p_lds[((q * 4 + 2) * 2 + khi) * 32 + b] = a2;
            p_lds[((q * 4 + 3) * 2 + khi) * 32 + b] = a3;
        }
        __syncthreads();
        if (t < 128) {
            const int jl = t >> 5, bb = t & 31;
            const float g0 = p_lds[((0 * 4 + jl) * 2 + 0) * 32 + bb]
                           + p_lds[((0 * 4 + jl) * 2 + 1) * 32 + bb] + xr0;
            const float g1 = p_lds[((1 * 4 + jl) * 2 + 0) * 32 + bb]
                           + p_lds[((1 * 4 + jl) * 2 + 1) * 32 + bb] + xr1;
            const float g2 = p_lds[((2 * 4 + jl) * 2 + 0) * 32 + bb]
                           + p_lds[((2 * 4 + jl) * 2 + 1) * 32 + bb] + xr2;
            const float g3 = p_lds[((3 * 4 + jl) * 2 + 0) * 32 + bb]
                           + p_lds[((3 * 4 + jl) * 2 + 1) * 32 + bb] + xr3;
            const float si = 1.0f / (1.0f + expf(-g0));
            const float sf = 1.0f / (1.0f + expf(-g1));
            const float so = 1.0f / (1.0f + expf(-g3));
            creg = sf * creg + si * tanhf(g2);
            const float hv = so * tanhf(creg);
            // cache-bypassing store -> LLC (device-visible, no L2 flush)
            __hip_atomic_store(&hsT[((long)step * Hh_ + 4 * bi + jl) * Bb_ + bb],
                               hv, __ATOMIC_RELAXED, __HIP_MEMORY_SCOPE_AGENT);
        }
        __syncthreads();   // drains vmcnt: h stores acked at LLC
        if (step == Tt_ - 1) break;   // last h already published for transpose
        if (t == 0) {
            __hip_atomic_store(&flags[bi], step + 1,
                               __ATOMIC_RELAXED, __HIP_MEMORY_SCOPE_AGENT);
        }
        for (;;) {
            int f = (t < 128)
                  ? __hip_atomic_load(&flags[t], __ATOMIC_RELAXED, __HIP_MEMORY_SCOPE_AGENT)
                  : 0x7fffffff;
            if (__syncthreads_count(f <= step) == 0) break;
        }
        __builtin_amdgcn_sched_barrier(0);
        // cached coalesced pull of fresh h (miss -> LLC, which is up to date)
        const float4* hsrc = (const float4*)(hsT + (long)step * Hh_ * Bb_);
        float4* hdst = (float4*)hT;
#pragma unroll
        for (int i = 0; i < 8; ++i) hdst[t + i * 512] = hsrc[t + i * 512];
        __syncthreads();
    }
}

// ---------------------------------------------------------------------------
// Transpose [T][H][B] -> [B][T][H]
// ---------------------------------------------------------------------------
__global__ __launch_bounds__(256) void transpose_kernel(
    const float* __restrict__ in, float* __restrict__ out)
{
    __shared__ float tile[32][33];
    const int tq = blockIdx.y;
    const int j0 = blockIdx.x * 32;
    const int t = threadIdx.x;
    for (int i = t; i < 1024; i += 256) {
        const int j = i >> 5, b = i & 31;
        tile[j][b] = in[((long)tq * Hh_ + j0 + j) * Bb_ + b];
    }
    __syncthreads();
    for (int i = t; i < 1024; i += 256) {
        const int b = i >> 5, j = i & 31;
        out[((long)b * Tt_ + tq) * Hh_ + j0 + j] = tile[j][b];
    }
}

// ---------------------------------------------------------------------------
// Row softmax over S=512. One block per row.
// ---------------------------------------------------------------------------
__global__ __launch_bounds__(256) void softmax_kernel(float* __restrict__ s)
{
    __shared__ float red[8];
    const long row = blockIdx.x;
    float* p = s + row * Ss_;
    const int t = threadIdx.x;
    float v0 = p[t], v1 = p[t + 256];
    float m = fmaxf(v0, v1);
    for (int off = 32; off; off >>= 1) m = fmaxf(m, __shfl_xor(m, off));
    if ((t & 63) == 0) red[t >> 6] = m;
    __syncthreads();
    m = fmaxf(fmaxf(red[0], red[1]), fmaxf(red[2], red[3]));
    const float e0 = expf(v0 - m), e1 = expf(v1 - m);
    float sm = e0 + e1;
    for (int off = 32; off; off >>= 1) sm += __shfl_xor(sm, off);
    if ((t & 63) == 0) red[4 + (t >> 6)] = sm;
    __syncthreads();
    const float inv = 1.0f / (red[4] + red[5] + red[6] + red[7]);
    p[t] = e0 * inv;
    p[t + 256] = e1 * inv;
}

// ---------------------------------------------------------------------------
// Concat: comb[m] = [hs1[m], attn_o[m]]
// ---------------------------------------------------------------------------
__global__ __launch_bounds__(256) void concat_kernel(
    const float* __restrict__ a, const float* __restrict__ bsrc,
    float* __restrict__ comb)
{
    const int idx = blockIdx.x * 256 + threadIdx.x;   // float4 index
    if (idx >= Bb_ * Tt_ * 256) return;
    const int m = idx >> 8, c = idx & 255;
    float4 v;
    if (c < 128) v = *(const float4*)(a + (long)m * Hh_ + (c << 2));
    else         v = *(const float4*)(bsrc + (long)m * Hh_ + ((c - 128) << 2));
    *(float4*)(comb + (long)m * 1024 + (c << 2)) = v;
}

// ---------------------------------------------------------------------------
static void gemm(hipStream_t s,
                 const float* A, int lda, long sAb, long sAh,
                 const float* B, int ldb, long sBb, long sBh, int transB,
                 float* C, int ldc, long sCb, long sCh,
                 int M, int N, int K, int NH, int Z,
                 const float* b1, const float* b2, int relu, float ps, int om)
{
    dim3 g(N / 64, (M + 127) / 128, Z);
    hipLaunchKernelGGL(gemm_kernel, g, dim3(256), 0, s,
                       A, lda, sAb, sAh, B, ldb, sBb, sBh, transB,
                       C, ldc, sCb, sCh, M, N, K, NH, b1, b2, relu, ps, om);
}

extern "C" void kernel_launch(void* const* d_in, const int* in_sizes, int n_in,
                              void* d_out, int out_size, void* d_ws, size_t ws_size,
                              hipStream_t stream)
{
    const float* enc_in  = (const float*)d_in[0];
    const int*   targets = (const int*)d_in[1];
    const float* emb     = (const float*)d_in[2];
    const float* Wih0    = (const float*)d_in[3];
    const float* Whh0    = (const float*)d_in[4];
    const float* bih0    = (const float*)d_in[5];
    const float* bhh0    = (const float*)d_in[6];
    const float* Wih1    = (const float*)d_in[7];
    const float* Whh1    = (const float*)d_in[8];
    const float* bih1    = (const float*)d_in[9];
    const float* bhh1    = (const float*)d_in[10];
    const float* attn_in_w  = (const float*)d_in[11];
    const float* attn_in_b  = (const float*)d_in[12];
    const float* attn_out_w = (const float*)d_in[13];
    const float* attn_out_b = (const float*)d_in[14];
    const float* encproj_w  = (const float*)d_in[15];
    const float* encproj_b  = (const float*)d_in[16];
    const float* out1_w     = (const float*)d_in[17];
    const float* out1_b     = (const float*)d_in[18];
    const float* out2_w     = (const float*)d_in[19];
    const float* out2_b     = (const float*)d_in[20];
    float* out = (float*)d_out;
    float* ws  = (float*)d_ws;

    // workspace layout (floats); total usage unchanged vs R1/R2 (~127 MB)
    const long SZ_A = 16384L * 512;       // 8,388,608
    float* enc   = ws;                    // region A
    float* kbuf  = ws + SZ_A;             // region B
    float* vbuf  = ws + 2 * SZ_A;         // region C
    float* xbuf  = ws;                    // A reuse (enc dead after k/v)
    float* xgT   = ws + 1638400;          // A upper ([T][4H][B] = 6,553,600)
    float* hsT0  = ws + 3 * SZ_A;                    // D
    float* hs0   = ws + 3 * SZ_A + 1 * 1638400L;     // E
    float* hsT1  = ws + 3 * SZ_A + 3 * 1638400L;     // G (NOT aliased to D)
    float* hs1   = ws + 3 * SZ_A + 2 * 1638400L;     // F (lstm_out)
    float* qbuf  = hs0;                              // E reuse (hs0 dead after xg1)
    float* scores = ws;                              // A reuse
    float* ctxb  = ws + 6553600;                     // A upper
    float* attn_o = hsT0;                            // D reuse
    float* comb  = kbuf;                             // B reuse
    float* h1    = kbuf + 3276800;                   // B upper
    int*   flags0 = (int*)(ws + 3 * SZ_A + 4 * 1638400L);  // region H
    int*   flags1 = flags0 + 256;

    const float qscale = 0.08838834764831845f;  // 1/sqrt(128)
    const size_t LSTM_LDS = (8192 + 16384 + 1024) * sizeof(float);  // 100 KB
    (void)hipFuncSetAttribute((const void*)lstm_kernel,
                              hipFuncAttributeMaxDynamicSharedMemorySize,
                              (int)LSTM_LDS);

    (void)hipMemsetAsync(flags0, 0, 512 * sizeof(int), stream);

    // 1. enc = encoder_outputs @ encproj_w^T + b      [16384,512]
    gemm(stream, enc_in, Ee_, 0, 0, encproj_w, Ee_, 0, 0, 1,
         enc, Hh_, 0, 0, Bb_ * Ss_, Hh_, Ee_, 1, 1,
         encproj_b, nullptr, 0, 1.0f, 0);
    // 2-3. k, v projections
    gemm(stream, enc, Hh_, 0, 0, attn_in_w + Hh_ * Hh_, Hh_, 0, 0, 1,
         kbuf, Hh_, 0, 0, Bb_ * Ss_, Hh_, Hh_, 1, 1,
         attn_in_b + Hh_, nullptr, 0, 1.0f, 0);
    gemm(stream, enc, Hh_, 0, 0, attn_in_w + 2 * Hh_ * Hh_, Hh_, 0, 0, 1,
         vbuf, Hh_, 0, 0, Bb_ * Ss_, Hh_, Hh_, 1, 1,
         attn_in_b + 2 * Hh_, nullptr, 0, 1.0f, 0);
    // 4. embedding
    hipLaunchKernelGGL(embed_kernel, dim3(1600), dim3(256), 0, stream,
                       targets, emb, xbuf);
    // 5. xg0 = x @ Wih0^T + biases -> xgT [T][4H][B]
    gemm(stream, xbuf, Hh_, 0, 0, Wih0, Hh_, 0, 0, 1,
         xgT, 0, 0, 0, Bb_ * Tt_, 4 * Hh_, Hh_, 1, 1,
         bih0, bhh0, 0, 1.0f, 1);
    // 6. LSTM layer 0 (128 blocks)
    {
        const float* a = xgT; const float* w = Whh0; float* o = hsT0; int* f = flags0;
        void* args[] = { (void*)&a, (void*)&w, (void*)&o, (void*)&f };
        hipLaunchCooperativeKernel((const void*)lstm_kernel, dim3(128), dim3(512),
                                   args, (unsigned int)LSTM_LDS, stream);
    }
    // 7. transpose hsT0 -> hs0 [B][T][H]
    hipLaunchKernelGGL(transpose_kernel, dim3(16, 100), dim3(256), 0, stream, hsT0, hs0);
    // 8. xg1 = hs0 @ Wih1^T + biases -> xgT
    gemm(stream, hs0, Hh_, 0, 0, Wih1, Hh_, 0, 0, 1,
         xgT, 0, 0, 0, Bb_ * Tt_, 4 * Hh_, Hh_, 1, 1,
         bih1, bhh1, 0, 1.0f, 1);
    // 9. LSTM layer 1
    {
        const float* a = xgT; const float* w = Whh1; float* o = hsT1; int* f = flags1;
        void* args[] = { (void*)&a, (void*)&w, (void*)&o, (void*)&f };
        hipLaunchCooperativeKernel((const void*)lstm_kernel, dim3(128), dim3(512),
                                   args, (unsigned int)LSTM_LDS, stream);
    }
    // 10. transpose hsT1 -> hs1
    hipLaunchKernelGGL(transpose_kernel, dim3(16, 100), dim3(256), 0, stream, hsT1, hs1);
    // 11. q = (hs1 @ Wq^T + bq) * qscale
    gemm(stream, hs1, Hh_, 0, 0, attn_in_w, Hh_, 0, 0, 1,
         qbuf, Hh_, 0, 0, Bb_ * Tt_, Hh_, Hh_, 1, 1,
         attn_in_b, nullptr, 0, qscale, 0);
    // 12. scores = q @ k^T per (b,head)
    gemm(stream, qbuf, Hh_, (long)Tt_ * Hh_, HDd_,
         kbuf, Hh_, (long)Ss_ * Hh_, HDd_, 1,
         scores, Ss_, (long)NHh_ * Tt_ * Ss_, (long)Tt_ * Ss_,
         Tt_, Ss_, HDd_, NHh_, Bb_ * NHh_,
         nullptr, nullptr, 0, 1.0f, 0);
    // 13. softmax rows
    hipLaunchKernelGGL(softmax_kernel, dim3(Bb_ * NHh_ * Tt_), dim3(256), 0, stream, scores);
    // 14. ctx = attn @ v per (b,head)
    gemm(stream, scores, Ss_, (long)NHh_ * Tt_ * Ss_, (long)Tt_ * Ss_,
         vbuf, Hh_, (long)Ss_ * Hh_, HDd_, 0,
         ctxb, Hh_, (long)Tt_ * Hh_, HDd_,
         Tt_, HDd_, Ss_, NHh_, Bb_ * NHh_,
         nullptr, nullptr, 0, 1.0f, 0);
    // 15. attn_out = ctx @ attn_out_w^T + b
    gemm(stream, ctxb, Hh_, 0, 0, attn_out_w, Hh_, 0, 0, 1,
         attn_o, Hh_, 0, 0, Bb_ * Tt_, Hh_, Hh_, 1, 1,
         attn_out_b, nullptr, 0, 1.0f, 0);
    // 16. combined = [hs1, attn_out]
    hipLaunchKernelGGL(concat_kernel, dim3(3200), dim3(256), 0, stream, hs1, attn_o, comb);
    // 17. h1 = relu(combined @ out1_w^T + b)
    gemm(stream, comb, 2 * Hh_, 0, 0, out1_w, 2 * Hh_, 0, 0, 1,
         h1, Hh_, 0, 0, Bb_ * Tt_, Hh_, 2 * Hh_, 1, 1,
         out1_b, nullptr, 1, 1.0f, 0);
    // 18. logits = h1 @ out2_w^T + b  -> d_out [3200][8192]
    gemm(stream, h1, Hh_, 0, 0, out2_w, Hh_, 0, 0, 1,
         out, Vv_, 0, 0, Bb_ * Tt_, Vv_, Hh_, 1, 1,
         out2_b, nullptr, 0, 1.0f, 0);
}

// Round 6
// 2615.186 us; speedup vs baseline: 2.9375x; 1.3064x over previous
//
#include <hip/hip_runtime.h>
#include <hip/hip_bf16.h>

// Problem dims
#define Bb_ 32
#define Tt_ 100
#define Ss_ 512
#define Ee_ 1024
#define Hh_ 512
#define Vv_ 8192
#define NHh_ 4
#define HDd_ 128

typedef __attribute__((ext_vector_type(8))) short short8v;
typedef __attribute__((ext_vector_type(4))) float f32x4;
typedef unsigned short ushort_t;

__device__ __forceinline__ ushort_t f2bf_rn(float x) {
    union { float f; unsigned u; } a; a.f = x;
    unsigned r = a.u + 0x7fffu + ((a.u >> 16) & 1u);
    return (ushort_t)(r >> 16);
}
__device__ __forceinline__ float bf2f(ushort_t h) {
    union { unsigned u; float f; } a; a.u = ((unsigned)h) << 16; return a.f;
}

// ---------------------------------------------------------------------------
// Weight split: fp32 -> bf16 hi + bf16 lo (round-nearest hi, residual lo)
// ---------------------------------------------------------------------------
__global__ __launch_bounds__(256) void split_kernel(
    const float* __restrict__ src, ushort_t* __restrict__ hi,
    ushort_t* __restrict__ lo, int n4)
{
    const int i = blockIdx.x * 256 + threadIdx.x;
    if (i >= n4) return;
    const float4 v = ((const float4*)src)[i];
    ushort4 h, l;
    h.x = f2bf_rn(v.x); l.x = f2bf_rn(v.x - bf2f(h.x));
    h.y = f2bf_rn(v.y); l.y = f2bf_rn(v.y - bf2f(h.y));
    h.z = f2bf_rn(v.z); l.z = f2bf_rn(v.z - bf2f(h.z));
    h.w = f2bf_rn(v.w); l.w = f2bf_rn(v.w - bf2f(h.w));
    ((ushort4*)hi)[i] = h;
    ((ushort4*)lo)[i] = l;
}

// ---------------------------------------------------------------------------
// Split-bf16 MFMA GEMM: C = A @ B^T + b1 + b2 (opt relu/scale).
// A fp32 [M][K] (split to hi/lo bf16 during LDS staging).
// B pre-split bf16 pair arrays, layout [N][K].
// Tile 128x128, BK=64, 256 threads (4 waves), 16x16x32 bf16 MFMA,
// 3 products per output frag: Ahi*Bhi + Ahi*Blo + Alo*Bhi.
// LDS rows 64 bf16 (128B), chunk XOR swizzle (c ^= r&7) -> ~2-way conflicts.
// out_mode 0: fp32 row-major; 1: fp32 xg scatter [T][4H][B].
// M, N must be multiples of 128; K of 64.
// ---------------------------------------------------------------------------
__global__ __launch_bounds__(256, 2) void gemm_mfma(
    const float* __restrict__ A, int lda,
    const ushort_t* __restrict__ Bhi, const ushort_t* __restrict__ Blo, int ldb,
    float* __restrict__ C, int ldc,
    int M, int N, int K,
    const float* __restrict__ bias1, const float* __restrict__ bias2,
    int relu, float post_scale, int out_mode)
{
    extern __shared__ ushort_t smem[];
    ushort_t* sAhi = smem;            // [128][64] bf16 = 8192 elems
    ushort_t* sAlo = smem + 8192;
    ushort_t* sBhi = smem + 16384;
    ushort_t* sBlo = smem + 24576;

    const int t = threadIdx.x;
    const int row0 = blockIdx.y * 128, col0 = blockIdx.x * 128;
    const int lane = t & 63;
    const int wv = t >> 6;
    const int wr = wv >> 1, wc = wv & 1;   // wave sub-tile (64x64)
    const int lr = lane & 15, lkc = lane >> 4;

    f32x4 acc[4][4] = {};

    for (int k0 = 0; k0 < K; k0 += 64) {
        // ---- global loads (4 slots A, 4 slots B per thread) ----
        float4 a0[4], a1[4];
        short8v bhr[4], blr[4];
#pragma unroll
        for (int rep = 0; rep < 4; ++rep) {
            const int s = t + 256 * rep;
            const int r = s >> 3, c = s & 7;
            const float* ap = A + (long)(row0 + r) * lda + k0 + c * 8;
            a0[rep] = *(const float4*)ap;
            a1[rep] = *(const float4*)(ap + 4);
            const long bo = (long)(col0 + r) * ldb + k0 + c * 8;
            bhr[rep] = *(const short8v*)(Bhi + bo);
            blr[rep] = *(const short8v*)(Blo + bo);
        }
        __syncthreads();   // prior iteration's LDS reads complete
        // ---- convert A to hi/lo, store all tiles to LDS (swizzled) ----
#pragma unroll
        for (int rep = 0; rep < 4; ++rep) {
            const int s = t + 256 * rep;
            const int r = s >> 3, c = s & 7;
            const int idx = r * 64 + ((c ^ (r & 7)) << 3);
            const float xs[8] = {a0[rep].x, a0[rep].y, a0[rep].z, a0[rep].w,
                                 a1[rep].x, a1[rep].y, a1[rep].z, a1[rep].w};
            short8v hv, lv;
#pragma unroll
            for (int j = 0; j < 8; ++j) {
                union { float f; unsigned u; } aa; aa.f = xs[j];
                const ushort_t h = (ushort_t)(aa.u >> 16);   // trunc hi
                hv[j] = (short)h;
                lv[j] = (short)f2bf_rn(xs[j] - bf2f(h));     // exact residual
            }
            *(short8v*)(sAhi + idx) = hv;
            *(short8v*)(sAlo + idx) = lv;
            *(short8v*)(sBhi + idx) = bhr[rep];
            *(short8v*)(sBlo + idx) = blr[rep];
        }
        __syncthreads();
        // ---- MFMA over the two K=32 halves ----
#pragma unroll
        for (int kh = 0; kh < 2; ++kh) {
            short8v ah[4], al[4];
#pragma unroll
            for (int mg = 0; mg < 4; ++mg) {
                const int ar = wr * 64 + mg * 16 + lr;
                const int idx = ar * 64 + ((((kh << 2) + lkc) ^ (ar & 7)) << 3);
                ah[mg] = *(const short8v*)(sAhi + idx);
                al[mg] = *(const short8v*)(sAlo + idx);
            }
#pragma unroll
            for (int ng = 0; ng < 4; ++ng) {
                const int br = wc * 64 + ng * 16 + lr;
                const int idx = br * 64 + ((((kh << 2) + lkc) ^ (br & 7)) << 3);
                const short8v bh = *(const short8v*)(sBhi + idx);
                const short8v bl = *(const short8v*)(sBlo + idx);
#pragma unroll
                for (int mg = 0; mg < 4; ++mg) {
                    acc[mg][ng] = __builtin_amdgcn_mfma_f32_16x16x32_bf16(al[mg], bh, acc[mg][ng], 0, 0, 0);
                    acc[mg][ng] = __builtin_amdgcn_mfma_f32_16x16x32_bf16(ah[mg], bl, acc[mg][ng], 0, 0, 0);
                    acc[mg][ng] = __builtin_amdgcn_mfma_f32_16x16x32_bf16(ah[mg], bh, acc[mg][ng], 0, 0, 0);
                }
            }
        }
    }

    // ---- epilogue: C/D layout col=lane&15, row=(lane>>4)*4+reg ----
#pragma unroll
    for (int mg = 0; mg < 4; ++mg) {
#pragma unroll
        for (int ng = 0; ng < 4; ++ng) {
#pragma unroll
            for (int j = 0; j < 4; ++j) {
                const int row = row0 + wr * 64 + mg * 16 + lkc * 4 + j;
                const int col = col0 + wc * 64 + ng * 16 + lr;
                float v = acc[mg][ng][j];
                if (bias1) v += bias1[col];
                if (bias2) v += bias2[col];
                v *= post_scale;
                if (relu) v = fmaxf(v, 0.0f);
                if (out_mode == 0) {
                    C[(long)row * ldc + col] = v;
                } else {
                    const int bq = row / Tt_, tq = row - bq * Tt_;
                    C[((long)tq * N + col) * Bb_ + bq] = v;
                }
            }
        }
    }
}

// ---------------------------------------------------------------------------
// fp32 GEMM (kept for small batched attention GEMMs): 128x64 tile.
// ---------------------------------------------------------------------------
__global__ __launch_bounds__(256) void gemm_kernel(
    const float* __restrict__ A, int lda, long sAb, long sAh,
    const float* __restrict__ B, int ldb, long sBb, long sBh, int transB,
    float* __restrict__ C, int ldc, long sCb, long sCh,
    int M, int N, int K, int NH,
    const float* __restrict__ bias1, const float* __restrict__ bias2,
    int relu, float post_scale, int out_mode)
{
    __shared__ float As[16][128];
    __shared__ float Bs[16][64];
    const int z = blockIdx.z;
    const int bz = z / NH, hz = z % NH;
    const float* Ab = A + (long)bz * sAb + (long)hz * sAh;
    const float* Bbp = B + (long)bz * sBb + (long)hz * sBh;
    float* Cb = C + (long)bz * sCb + (long)hz * sCh;

    const int row0 = blockIdx.y * 128, col0 = blockIdx.x * 64;
    const int t = threadIdx.x;
    const int ar = t >> 1, ac = (t & 1) * 8;
    const int bc = t >> 2, bk = (t & 3) * 4;
    const int brow = t >> 4, bcol = (t & 15) * 4;
    const int ty = t >> 4, tx = t & 15;

    float acc[8][4] = {};

    for (int k0 = 0; k0 < K; k0 += 16) {
        int am = row0 + ar; if (am >= M) am = M - 1;
        const float4 av0 = *(const float4*)(Ab + (long)am * lda + k0 + ac);
        const float4 av1 = *(const float4*)(Ab + (long)am * lda + k0 + ac + 4);
        float4 bv;
        if (transB) bv = *(const float4*)(Bbp + (long)(col0 + bc) * ldb + k0 + bk);
        else        bv = *(const float4*)(Bbp + (long)(k0 + brow) * ldb + col0 + bcol);
        __syncthreads();
        As[ac + 0][ar] = av0.x; As[ac + 1][ar] = av0.y;
        As[ac + 2][ar] = av0.z; As[ac + 3][ar] = av0.w;
        As[ac + 4][ar] = av1.x; As[ac + 5][ar] = av1.y;
        As[ac + 6][ar] = av1.z; As[ac + 7][ar] = av1.w;
        if (transB) {
            Bs[bk + 0][bc] = bv.x; Bs[bk + 1][bc] = bv.y;
            Bs[bk + 2][bc] = bv.z; Bs[bk + 3][bc] = bv.w;
        } else {
            *(float4*)&Bs[brow][bcol] = bv;
        }
        __syncthreads();
#pragma unroll
        for (int kk = 0; kk < 16; ++kk) {
            const float4 a4  = *(const float4*)&As[kk][ty * 8];
            const float4 a4b = *(const float4*)&As[kk][ty * 8 + 4];
            const float4 b4  = *(const float4*)&Bs[kk][tx * 4];
            const float af[8] = {a4.x, a4.y, a4.z, a4.w, a4b.x, a4b.y, a4b.z, a4b.w};
            const float bf[4] = {b4.x, b4.y, b4.z, b4.w};
#pragma unroll
            for (int i = 0; i < 8; ++i)
#pragma unroll
                for (int j = 0; j < 4; ++j)
                    acc[i][j] = fmaf(af[i], bf[j], acc[i][j]);
        }
    }

#pragma unroll
    for (int i = 0; i < 8; ++i) {
        const int m = row0 + ty * 8 + i;
        if (m >= M) continue;
#pragma unroll
        for (int j = 0; j < 4; ++j) {
            const int n = col0 + tx * 4 + j;
            float v = acc[i][j];
            if (bias1) v += bias1[n];
            if (bias2) v += bias2[n];
            v *= post_scale;
            if (relu) v = fmaxf(v, 0.0f);
            if (out_mode == 0) {
                Cb[(long)m * ldc + n] = v;
            } else {
                const int bq = m / Tt_, tq = m - bq * Tt_;
                C[((long)tq * N + n) * Bb_ + bq] = v;
            }
        }
    }
}

// ---------------------------------------------------------------------------
// Embedding lookup: x[m][:] = emb[targets[m]][:]
// ---------------------------------------------------------------------------
__global__ __launch_bounds__(256) void embed_kernel(
    const int* __restrict__ tgt, const float* __restrict__ emb,
    float* __restrict__ x)
{
    const int idx = blockIdx.x * 256 + threadIdx.x;   // float4 index
    if (idx >= Bb_ * Tt_ * (Hh_ / 4)) return;
    const int m = idx >> 7, c = idx & 127;
    const int token = tgt[m];
    *(float4*)(x + (long)m * Hh_ + (c << 2)) =
        *(const float4*)(emb + (long)token * Hh_ + (c << 2));
}

// ---------------------------------------------------------------------------
// LSTM recurrence (unchanged from R3). 128 blocks x 512 threads.
// ---------------------------------------------------------------------------
__global__ __launch_bounds__(512) void lstm_kernel(
    const float* __restrict__ xgT, const float* __restrict__ Whh,
    float* __restrict__ hsT, int* __restrict__ flags)
{
    extern __shared__ float lds[];
    float* w_lds = lds;                   // [16][512] = 8192
    float* hT    = lds + 8192;            // [512][32] = 16384
    float* p_lds = lds + 8192 + 16384;    // [16][2][32] = 1024

    const int t  = threadIdx.x;
    const int bi = blockIdx.x;            // 0..127
    const int b  = t & 31;
    const int kq = (t >> 5) & 3;
    const int q  = t >> 7;

    for (int i = t; i < 8192; i += 512) {
        const int r = i >> 9, k = i & 511;
        w_lds[i] = Whh[((long)((r >> 2) * Hh_ + 4 * bi + (r & 3))) * Hh_ + k];
    }
    for (int i = t; i < 16384; i += 512) hT[i] = 0.0f;

    float creg = 0.0f;
    __syncthreads();

    const float* wb0 = w_lds + (q * 4 + 0) * 512 + kq * 128;
    const float* wb1 = w_lds + (q * 4 + 1) * 512 + kq * 128;
    const float* wb2 = w_lds + (q * 4 + 2) * 512 + kq * 128;
    const float* wb3 = w_lds + (q * 4 + 3) * 512 + kq * 128;

    for (int step = 0; step < Tt_; ++step) {
        float xr0 = 0.f, xr1 = 0.f, xr2 = 0.f, xr3 = 0.f;
        if (t < 128) {
            const int jl = t >> 5;
            const long xb = (long)step * (4 * Hh_) * Bb_
                          + (long)(4 * bi + jl) * Bb_ + (t & 31);
            xr0 = xgT[xb];
            xr1 = xgT[xb + 512 * Bb_];
            xr2 = xgT[xb + 1024 * Bb_];
            xr3 = xgT[xb + 1536 * Bb_];
        }
        float a0 = 0.f, a1 = 0.f, a2 = 0.f, a3 = 0.f;
#pragma unroll 4
        for (int k = 0; k < 128; k += 8) {
            const float4 w00 = *(const float4*)(wb0 + k);
            const float4 w01 = *(const float4*)(wb0 + k + 4);
            const float4 w10 = *(const float4*)(wb1 + k);
            const float4 w11 = *(const float4*)(wb1 + k + 4);
            const float4 w20 = *(const float4*)(wb2 + k);
            const float4 w21 = *(const float4*)(wb2 + k + 4);
            const float4 w30 = *(const float4*)(wb3 + k);
            const float4 w31 = *(const float4*)(wb3 + k + 4);
            const int kk = (kq * 128 + k) * 32 + b;
            const float h0 = hT[kk];       const float h1v = hT[kk + 32];
            const float h2 = hT[kk + 64];  const float h3 = hT[kk + 96];
            const float h4 = hT[kk + 128]; const float h5 = hT[kk + 160];
            const float h6 = hT[kk + 192]; const float h7 = hT[kk + 224];
            a0 = fmaf(w00.x, h0, a0); a0 = fmaf(w00.y, h1v, a0);
            a0 = fmaf(w00.z, h2, a0); a0 = fmaf(w00.w, h3, a0);
            a0 = fmaf(w01.x, h4, a0); a0 = fmaf(w01.y, h5, a0);
            a0 = fmaf(w01.z, h6, a0); a0 = fmaf(w01.w, h7, a0);
            a1 = fmaf(w10.x, h0, a1); a1 = fmaf(w10.y, h1v, a1);
            a1 = fmaf(w10.z, h2, a1); a1 = fmaf(w10.w, h3, a1);
            a1 = fmaf(w11.x, h4, a1); a1 = fmaf(w11.y, h5, a1);
            a1 = fmaf(w11.z, h6, a1); a1 = fmaf(w11.w, h7, a1);
            a2 = fmaf(w20.x, h0, a2); a2 = fmaf(w20.y, h1v, a2);
            a2 = fmaf(w20.z, h2, a2); a2 = fmaf(w20.w, h3, a2);
            a2 = fmaf(w21.x, h4, a2); a2 = fmaf(w21.y, h5, a2);
            a2 = fmaf(w21.z, h6, a2); a2 = fmaf(w21.w, h7, a2);
            a3 = fmaf(w30.x, h0, a3); a3 = fmaf(w30.y, h1v, a3);
            a3 = fmaf(w30.z, h2, a3); a3 = fmaf(w30.w, h3, a3);
            a3 = fmaf(w31.x, h4, a3); a3 = fmaf(w31.y, h5, a3);
            a3 = fmaf(w31.z, h6, a3); a3 = fmaf(w31.w, h7, a3);
        }
        a0 += __shfl_xor(a0, 32);
        a1 += __shfl_xor(a1, 32);
        a2 += __shfl_xor(a2, 32);
        a3 += __shfl_xor(a3, 32);
        if ((t & 32) == 0) {
            const int khi = (t >> 6) & 1;
            p_lds[((q * 4 + 0) * 2 + khi) * 32 + b] = a0;
            p_lds[((q * 4 + 1) * 2 + khi) * 32 + b] = a1;
            p_lds[((q * 4 + 2) * 2 + khi) * 32 + b] = a2;
            p_lds[((q * 4 + 3) * 2 + khi) * 32 + b] = a3;
        }
        __syncthreads();
        if (t < 128) {
            const int jl = t >> 5, bb = t & 31;
            const float g0 = p_lds[((0 * 4 + jl) * 2 + 0) * 32 + bb]
                           + p_lds[((0 * 4 + jl) * 2 + 1) * 32 + bb] + xr0;
            const float g1 = p_lds[((1 * 4 + jl) * 2 + 0) * 32 + bb]
                           + p_lds[((1 * 4 + jl) * 2 + 1) * 32 + bb] + xr1;
            const float g2 = p_lds[((2 * 4 + jl) * 2 + 0) * 32 + bb]
                           + p_lds[((2 * 4 + jl) * 2 + 1) * 32 + bb] + xr2;
            const float g3 = p_lds[((3 * 4 + jl) * 2 + 0) * 32 + bb]
                           + p_lds[((3 * 4 + jl) * 2 + 1) * 32 + bb] + xr3;
            const float si = 1.0f / (1.0f + expf(-g0));
            const float sf = 1.0f / (1.0f + expf(-g1));
            const float so = 1.0f / (1.0f + expf(-g3));
            creg = sf * creg + si * tanhf(g2);
            const float hv = so * tanhf(creg);
            __hip_atomic_store(&hsT[((long)step * Hh_ + 4 * bi + jl) * Bb_ + bb],
                               hv, __ATOMIC_RELAXED, __HIP_MEMORY_SCOPE_AGENT);
        }
        __syncthreads();
        if (step == Tt_ - 1) break;
        if (t == 0) {
            __hip_atomic_store(&flags[bi], step + 1,
                               __ATOMIC_RELAXED, __HIP_MEMORY_SCOPE_AGENT);
        }
        for (;;) {
            int f = (t < 128)
                  ? __hip_atomic_load(&flags[t], __ATOMIC_RELAXED, __HIP_MEMORY_SCOPE_AGENT)
                  : 0x7fffffff;
            if (__syncthreads_count(f <= step) == 0) break;
        }
        __builtin_amdgcn_sched_barrier(0);
        const float4* hsrc = (const float4*)(hsT + (long)step * Hh_ * Bb_);
        float4* hdst = (float4*)hT;
#pragma unroll
        for (int i = 0; i < 8; ++i) hdst[t + i * 512] = hsrc[t + i * 512];
        __syncthreads();
    }
}

// ---------------------------------------------------------------------------
// Transpose [T][H][B] -> [B][T][H]
// ---------------------------------------------------------------------------
__global__ __launch_bounds__(256) void transpose_kernel(
    const float* __restrict__ in, float* __restrict__ out)
{
    __shared__ float tile[32][33];
    const int tq = blockIdx.y;
    const int j0 = blockIdx.x * 32;
    const int t = threadIdx.x;
    for (int i = t; i < 1024; i += 256) {
        const int j = i >> 5, b = i & 31;
        tile[j][b] = in[((long)tq * Hh_ + j0 + j) * Bb_ + b];
    }
    __syncthreads();
    for (int i = t; i < 1024; i += 256) {
        const int b = i >> 5, j = i & 31;
        out[((long)b * Tt_ + tq) * Hh_ + j0 + j] = tile[j][b];
    }
}

// ---------------------------------------------------------------------------
// Row softmax over S=512. One block per row.
// ---------------------------------------------------------------------------
__global__ __launch_bounds__(256) void softmax_kernel(float* __restrict__ s)
{
    __shared__ float red[8];
    const long row = blockIdx.x;
    float* p = s + row * Ss_;
    const int t = threadIdx.x;
    float v0 = p[t], v1 = p[t + 256];
    float m = fmaxf(v0, v1);
    for (int off = 32; off; off >>= 1) m = fmaxf(m, __shfl_xor(m, off));
    if ((t & 63) == 0) red[t >> 6] = m;
    __syncthreads();
    m = fmaxf(fmaxf(red[0], red[1]), fmaxf(red[2], red[3]));
    const float e0 = expf(v0 - m), e1 = expf(v1 - m);
    float sm = e0 + e1;
    for (int off = 32; off; off >>= 1) sm += __shfl_xor(sm, off);
    if ((t & 63) == 0) red[4 + (t >> 6)] = sm;
    __syncthreads();
    const float inv = 1.0f / (red[4] + red[5] + red[6] + red[7]);
    p[t] = e0 * inv;
    p[t + 256] = e1 * inv;
}

// ---------------------------------------------------------------------------
// Concat: comb[m] = [hs1[m], attn_o[m]]
// ---------------------------------------------------------------------------
__global__ __launch_bounds__(256) void concat_kernel(
    const float* __restrict__ a, const float* __restrict__ bsrc,
    float* __restrict__ comb)
{
    const int idx = blockIdx.x * 256 + threadIdx.x;   // float4 index
    if (idx >= Bb_ * Tt_ * 256) return;
    const int m = idx >> 8, c = idx & 255;
    float4 v;
    if (c < 128) v = *(const float4*)(a + (long)m * Hh_ + (c << 2));
    else         v = *(const float4*)(bsrc + (long)m * Hh_ + ((c - 128) << 2));
    *(float4*)(comb + (long)m * 1024 + (c << 2)) = v;
}

// ---------------------------------------------------------------------------
static void gemm(hipStream_t s,
                 const float* A, int lda, long sAb, long sAh,
                 const float* B, int ldb, long sBb, long sBh, int transB,
                 float* C, int ldc, long sCb, long sCh,
                 int M, int N, int K, int NH, int Z,
                 const float* b1, const float* b2, int relu, float ps, int om)
{
    dim3 g(N / 64, (M + 127) / 128, Z);
    hipLaunchKernelGGL(gemm_kernel, g, dim3(256), 0, s,
                       A, lda, sAb, sAh, B, ldb, sBb, sBh, transB,
                       C, ldc, sCb, sCh, M, N, K, NH, b1, b2, relu, ps, om);
}

static void gemm_bf(hipStream_t s,
                    const float* A, int lda,
                    const ushort_t* Bhi, const ushort_t* Blo, int ldb,
                    float* C, int ldc, int M, int N, int K,
                    const float* b1, const float* b2, int relu, float ps, int om)
{
    dim3 g(N / 128, M / 128);
    hipLaunchKernelGGL(gemm_mfma, g, dim3(256), 65536, s,
                       A, lda, Bhi, Blo, ldb, C, ldc, M, N, K,
                       b1, b2, relu, ps, om);
}

extern "C" void kernel_launch(void* const* d_in, const int* in_sizes, int n_in,
                              void* d_out, int out_size, void* d_ws, size_t ws_size,
                              hipStream_t stream)
{
    const float* enc_in  = (const float*)d_in[0];
    const int*   targets = (const int*)d_in[1];
    const float* emb     = (const float*)d_in[2];
    const float* Wih0    = (const float*)d_in[3];
    const float* Whh0    = (const float*)d_in[4];
    const float* bih0    = (const float*)d_in[5];
    const float* bhh0    = (const float*)d_in[6];
    const float* Wih1    = (const float*)d_in[7];
    const float* Whh1    = (const float*)d_in[8];
    const float* bih1    = (const float*)d_in[9];
    const float* bhh1    = (const float*)d_in[10];
    const float* attn_in_w  = (const float*)d_in[11];
    const float* attn_in_b  = (const float*)d_in[12];
    const float* attn_out_w = (const float*)d_in[13];
    const float* attn_out_b = (const float*)d_in[14];
    const float* encproj_w  = (const float*)d_in[15];
    const float* encproj_b  = (const float*)d_in[16];
    const float* out1_w     = (const float*)d_in[17];
    const float* out1_b     = (const float*)d_in[18];
    const float* out2_w     = (const float*)d_in[19];
    const float* out2_b     = (const float*)d_in[20];
    float* out = (float*)d_out;
    float* ws  = (float*)d_ws;

    // workspace layout (float units), ~160 MB total
    const long SZ_A = 8388608L;
    float* enc   = ws;                               // region A
    float* xbuf  = ws;                               // A reuse
    float* xgT   = ws + 1638400;                     // A upper
    float* scores = ws;                              // A reuse (attention phase)
    float* ctxb  = ws + 6553600;                     // A upper
    float* kbuf  = ws + SZ_A;                        // region B
    float* comb  = kbuf;                             // B reuse
    float* h1    = kbuf + 3276800;                   // B upper
    float* vbuf  = ws + 2 * SZ_A;                    // region C
    float* hsT0  = ws + 3 * SZ_A;                    // region D
    float* hs0   = ws + 3 * SZ_A + 1638400L;
    float* hs1   = ws + 3 * SZ_A + 2 * 1638400L;
    float* hsT1  = ws + 3 * SZ_A + 3 * 1638400L;
    float* qbuf  = hs0;                              // reuse
    float* attn_o = hsT0;                            // reuse
    int*   flags0 = (int*)(ws + 3 * SZ_A + 4 * 1638400L);
    int*   flags1 = flags0 + 256;
    // weight bf16-pair region
    const long WOFF = 3 * SZ_A + 4 * 1638400L + 512;
    ushort_t* Whi = (ushort_t*)(ws + WOFF);
    ushort_t* Wlo = Whi + 8388608L;
    const long OW_ENCP   = 0;
    const long OW_ATTNIN = 524288;
    const long OW_WIH0   = 1310720;
    const long OW_WIH1   = 2359296;
    const long OW_ATTNO  = 3407872;
    const long OW_OUT1   = 3670016;
    const long OW_OUT2   = 4194304;

    const float qscale = 0.08838834764831845f;  // 1/sqrt(128)
    const size_t LSTM_LDS = (8192 + 16384 + 1024) * sizeof(float);  // 100 KB
    (void)hipFuncSetAttribute((const void*)lstm_kernel,
                              hipFuncAttributeMaxDynamicSharedMemorySize,
                              (int)LSTM_LDS);
    (void)hipFuncSetAttribute((const void*)gemm_mfma,
                              hipFuncAttributeMaxDynamicSharedMemorySize, 65536);

    (void)hipMemsetAsync(flags0, 0, 512 * sizeof(int), stream);

    // 0. split all weights to bf16 hi/lo
    {
        struct { const float* src; long off; int n; } sp[7] = {
            { encproj_w,  OW_ENCP,   524288 },
            { attn_in_w,  OW_ATTNIN, 786432 },
            { Wih0,       OW_WIH0,   1048576 },
            { Wih1,       OW_WIH1,   1048576 },
            { attn_out_w, OW_ATTNO,  262144 },
            { out1_w,     OW_OUT1,   524288 },
            { out2_w,     OW_OUT2,   4194304 },
        };
        for (int i = 0; i < 7; ++i) {
            const int n4 = sp[i].n / 4;
            hipLaunchKernelGGL(split_kernel, dim3((n4 + 255) / 256), dim3(256), 0,
                               stream, sp[i].src, Whi + sp[i].off, Wlo + sp[i].off, n4);
        }
    }

    // 1. enc = enc_in @ encproj_w^T + b   [16384,512]
    gemm_bf(stream, enc_in, Ee_, Whi + OW_ENCP, Wlo + OW_ENCP, Ee_,
            enc, Hh_, Bb_ * Ss_, Hh_, Ee_, encproj_b, nullptr, 0, 1.0f, 0);
    // 2-3. k, v projections
    gemm_bf(stream, enc, Hh_, Whi + OW_ATTNIN + 262144, Wlo + OW_ATTNIN + 262144, Hh_,
            kbuf, Hh_, Bb_ * Ss_, Hh_, Hh_, attn_in_b + Hh_, nullptr, 0, 1.0f, 0);
    gemm_bf(stream, enc, Hh_, Whi + OW_ATTNIN + 524288, Wlo + OW_ATTNIN + 524288, Hh_,
            vbuf, Hh_, Bb_ * Ss_, Hh_, Hh_, attn_in_b + 2 * Hh_, nullptr, 0, 1.0f, 0);
    // 4. embedding (A region reuse; enc dead after v)
    hipLaunchKernelGGL(embed_kernel, dim3(1600), dim3(256), 0, stream,
                       targets, emb, xbuf);
    // 5. xg0 = x @ Wih0^T + biases -> xgT [T][4H][B]
    gemm_bf(stream, xbuf, Hh_, Whi + OW_WIH0, Wlo + OW_WIH0, Hh_,
            xgT, 0, Bb_ * Tt_, 4 * Hh_, Hh_, bih0, bhh0, 0, 1.0f, 1);
    // 6. LSTM layer 0
    {
        const float* a = xgT; const float* w = Whh0; float* o = hsT0; int* f = flags0;
        void* args[] = { (void*)&a, (void*)&w, (void*)&o, (void*)&f };
        hipLaunchCooperativeKernel((const void*)lstm_kernel, dim3(128), dim3(512),
                                   args, (unsigned int)LSTM_LDS, stream);
    }
    // 7. transpose hsT0 -> hs0
    hipLaunchKernelGGL(transpose_kernel, dim3(16, 100), dim3(256), 0, stream, hsT0, hs0);
    // 8. xg1 = hs0 @ Wih1^T + biases -> xgT
    gemm_bf(stream, hs0, Hh_, Whi + OW_WIH1, Wlo + OW_WIH1, Hh_,
            xgT, 0, Bb_ * Tt_, 4 * Hh_, Hh_, bih1, bhh1, 0, 1.0f, 1);
    // 9. LSTM layer 1
    {
        const float* a = xgT; const float* w = Whh1; float* o = hsT1; int* f = flags1;
        void* args[] = { (void*)&a, (void*)&w, (void*)&o, (void*)&f };
        hipLaunchCooperativeKernel((const void*)lstm_kernel, dim3(128), dim3(512),
                                   args, (unsigned int)LSTM_LDS, stream);
    }
    // 10. transpose hsT1 -> hs1
    hipLaunchKernelGGL(transpose_kernel, dim3(16, 100), dim3(256), 0, stream, hsT1, hs1);
    // 11. q = (hs1 @ Wq^T + bq) * qscale   (hs0 region reused as qbuf)
    gemm_bf(stream, hs1, Hh_, Whi + OW_ATTNIN, Wlo + OW_ATTNIN, Hh_,
            qbuf, Hh_, Bb_ * Tt_, Hh_, Hh_, attn_in_b, nullptr, 0, qscale, 0);
    // 12. scores = q @ k^T per (b,head)  [fp32 path]
    gemm(stream, qbuf, Hh_, (long)Tt_ * Hh_, HDd_,
         kbuf, Hh_, (long)Ss_ * Hh_, HDd_, 1,
         scores, Ss_, (long)NHh_ * Tt_ * Ss_, (long)Tt_ * Ss_,
         Tt_, Ss_, HDd_, NHh_, Bb_ * NHh_,
         nullptr, nullptr, 0, 1.0f, 0);
    // 13. softmax rows
    hipLaunchKernelGGL(softmax_kernel, dim3(Bb_ * NHh_ * Tt_), dim3(256), 0, stream, scores);
    // 14. ctx = attn @ v per (b,head)  [fp32 path]
    gemm(stream, scores, Ss_, (long)NHh_ * Tt_ * Ss_, (long)Tt_ * Ss_,
         vbuf, Hh_, (long)Ss_ * Hh_, HDd_, 0,
         ctxb, Hh_, (long)Tt_ * Hh_, HDd_,
         Tt_, HDd_, Ss_, NHh_, Bb_ * NHh_,
         nullptr, nullptr, 0, 1.0f, 0);
    // 15. attn_out = ctx @ attn_out_w^T + b
    gemm_bf(stream, ctxb, Hh_, Whi + OW_ATTNO, Wlo + OW_ATTNO, Hh_,
            attn_o, Hh_, Bb_ * Tt_, Hh_, Hh_, attn_out_b, nullptr, 0, 1.0f, 0);
    // 16. combined = [hs1, attn_out]
    hipLaunchKernelGGL(concat_kernel, dim3(3200), dim3(256), 0, stream, hs1, attn_o, comb);
    // 17. h1 = relu(combined @ out1_w^T + b)
    gemm_bf(stream, comb, 2 * Hh_, Whi + OW_OUT1, Wlo + OW_OUT1, 2 * Hh_,
            h1, Hh_, Bb_ * Tt_, Hh_, 2 * Hh_, out1_b, nullptr, 1, 1.0f, 0);
    // 18. logits = h1 @ out2_w^T + b -> d_out [3200][8192]
    gemm_bf(stream, h1, Hh_, Whi + OW_OUT2, Wlo + OW_OUT2, Hh_,
            out, Vv_, Bb_ * Tt_, Vv_, Hh_, out2_b, nullptr, 0, 1.0f, 0);
}